// Round 8
// baseline (397.212 us; speedup 1.0000x reference)
//
#include <hip/hip_runtime.h>

typedef unsigned short u16;
typedef unsigned int u32;
typedef __attribute__((ext_vector_type(8))) short short8;
typedef __attribute__((ext_vector_type(4))) float floatx4;

// ---------- bf16 helpers ----------
__device__ __forceinline__ float b2f(u32 bits) { union { u32 u; float f; } c; c.u = bits << 16; return c.f; }
__device__ __forceinline__ float b2f_lo(u32 w) { union { u32 u; float f; } c; c.u = w << 16; return c.f; }
__device__ __forceinline__ float b2f_hi(u32 w) { union { u32 u; float f; } c; c.u = w & 0xFFFF0000u; return c.f; }
__device__ __forceinline__ u16 f2b(float f) {
    union { float f; u32 u; } c; c.f = f;
    u32 u = c.u;
    return (u16)((u + 0x7FFFu + ((u >> 16) & 1u)) >> 16);   // RNE
}
// packed bf16 mul, round-half-up (bias ~2^-16 rel)
__device__ __forceinline__ u32 pkmul(u32 a, u32 b) {
    union { u32 u; float f; } alo, ahi, blo, bhi, rlo, rhi;
    alo.u = a << 16; ahi.u = a & 0xFFFF0000u;
    blo.u = b << 16; bhi.u = b & 0xFFFF0000u;
    rlo.f = alo.f * blo.f; rhi.f = ahi.f * bhi.f;
    u32 lo = rlo.u + 0x8000u, hi = rhi.u + 0x8000u;
    return __builtin_amdgcn_perm(hi, lo, 0x07060302u);
}
// async global->LDS, 16B per lane; lds base must be wave-uniform
__device__ __forceinline__ void gld_lds16(const u16* g, u16* l) {
    __builtin_amdgcn_global_load_lds((const __attribute__((address_space(1))) u32*)g,
                                     (__attribute__((address_space(3))) u32*)l, 16, 0, 0);
}

// ---------- graph prep ----------
__global__ __launch_bounds__(256) void count_deg(const int* __restrict__ row, int* __restrict__ cnt, int E) {
    int e = blockIdx.x * 256 + threadIdx.x;
    if (e < E) atomicAdd(&cnt[row[e]], 1);
}

// CSR segment allocation WITHOUT ordered scan: wave-prefix + 1 atomic bump per wave.
__global__ __launch_bounds__(256) void alloc_offs(const int* __restrict__ cnt, int* __restrict__ offs,
                                                  float* __restrict__ dinv, int* __restrict__ gcur, int N) {
    int i = blockIdx.x * 256 + threadIdx.x;
    int lane = threadIdx.x & 63;
    int c = (i < N) ? cnt[i] : 0;
    int sc = c;
#pragma unroll
    for (int o = 1; o < 64; o <<= 1) {
        int u = __shfl_up(sc, o, 64);
        if (lane >= o) sc += u;
    }
    int ex = sc - c;                       // exclusive prefix within wave
    int total = __shfl(sc, 63, 64);        // wave total
    int base = 0;
    if (lane == 63) base = atomicAdd(gcur, total);
    base = __shfl(base, 63, 64);
    if (i < N) {
        offs[i] = base + ex;
        dinv[i] = rsqrtf((float)c + 1.0f);
    }
}

__global__ __launch_bounds__(256) void sort_edges(const int* __restrict__ row, const int* __restrict__ col,
                                                  const int* __restrict__ offs, int* __restrict__ cursor,
                                                  int* __restrict__ scol, int E) {
    int e = blockIdx.x * 256 + threadIdx.x;
    if (e < E) {
        int r = row[e];
        int p = offs[r] + atomicAdd(&cursor[r], 1);
        scol[p] = col[e];
    }
}

// ---------- fused weight prep + h0 concat (one launch) ----------
__global__ __launch_bounds__(256) void prep_wh(const float* __restrict__ W1, const float* __restrict__ W2,
                                               const float* __restrict__ pW1, u16* __restrict__ WT,
                                               const float* __restrict__ emb, const float* __restrict__ x,
                                               u16* __restrict__ h0b, int N) {
    int b = blockIdx.x;
    if (b < 768) {
        int tid = b * 256 + threadIdx.x;
        int which = tid >> 16, id = tid & 65535;
        int n = id >> 8, k = id & 255;
        const float* W = (which == 0) ? W1 : ((which == 1) ? W2 : pW1);
        WT[tid] = f2b(W[k * 256 + n]);
    } else {
        int t = (b - 768) * 256 + threadIdx.x;
        long base = (long)t * 4;
        if (base >= (long)N * 256) return;
        int i = (int)(base >> 8), k = (int)(base & 255);
        const float* src = (k < 128) ? (emb + (long)i * 128 + k) : (x + (long)i * 128 + (k - 128));
        float4 v = *(const float4*)src;
        ushort4 o;
        o.x = f2b(v.x); o.y = f2b(v.y); o.z = f2b(v.z); o.w = f2b(v.w);
        *(ushort4*)(h0b + base) = o;
    }
}

// ---------- aggregation: 1 node per half-wave (32 lanes x uint4 = full 512B row) ----------
template <int FUSED_BN>
__global__ __launch_bounds__(256) void aggregate2(const u16* __restrict__ h, const int* __restrict__ offs,
                                                  const int* __restrict__ cnt, const int* __restrict__ scol,
                                                  const float* __restrict__ dinv, const float* __restrict__ coef,
                                                  u16* __restrict__ out, int N) {
    int hw = threadIdx.x >> 5, lane = threadIdx.x & 31;
    int node = blockIdx.x * 8 + hw;
    if (node >= N) return;
    float sc[8], sh[8];
    if (FUSED_BN) {
#pragma unroll
        for (int i = 0; i < 8; i++) { sc[i] = coef[lane * 8 + i]; sh[i] = coef[256 + lane * 8 + i]; }
    }
    float a[8];
#pragma unroll
    for (int i = 0; i < 8; i++) a[i] = 0.f;

    auto rowAcc = [&](uint4 u, float d) {
        float f[8];
        f[0] = b2f_lo(u.x); f[1] = b2f_hi(u.x);
        f[2] = b2f_lo(u.y); f[3] = b2f_hi(u.y);
        f[4] = b2f_lo(u.z); f[5] = b2f_hi(u.z);
        f[6] = b2f_lo(u.w); f[7] = b2f_hi(u.w);
#pragma unroll
        for (int i = 0; i < 8; i++) {
            float v = f[i];
            if (FUSED_BN) v = fmaxf(fmaf(v, sc[i], sh[i]), 0.f);
            a[i] = fmaf(v, d, a[i]);
        }
    };
    int beg = offs[node], end = beg + cnt[node];
    int j = beg;
    for (; j + 3 < end; j += 4) {
        int c0 = scol[j], c1 = scol[j + 1], c2 = scol[j + 2], c3 = scol[j + 3];
        float d0 = dinv[c0], d1 = dinv[c1], d2 = dinv[c2], d3 = dinv[c3];
        uint4 v0 = *(const uint4*)(h + (long)c0 * 256 + lane * 8);
        uint4 v1 = *(const uint4*)(h + (long)c1 * 256 + lane * 8);
        uint4 v2 = *(const uint4*)(h + (long)c2 * 256 + lane * 8);
        uint4 v3 = *(const uint4*)(h + (long)c3 * 256 + lane * 8);
        rowAcc(v0, d0); rowAcc(v1, d1); rowAcc(v2, d2); rowAcc(v3, d3);
    }
    for (; j < end; j++) {
        int c0 = scol[j];
        float d0 = dinv[c0];
        uint4 v0 = *(const uint4*)(h + (long)c0 * 256 + lane * 8);
        rowAcc(v0, d0);
    }
    float di = dinv[node];
    {
        uint4 u = *(const uint4*)(h + (long)node * 256 + lane * 8);
        rowAcc(u, di);   // self term with weight di (total = sum + di*self)
    }
    u16 ob[8];
#pragma unroll
    for (int i = 0; i < 8; i++) ob[i] = f2b(di * a[i]);
    ushort4 o0, o1;
    o0.x = ob[0]; o0.y = ob[1]; o0.z = ob[2]; o0.w = ob[3];
    o1.x = ob[4]; o1.y = ob[5]; o1.z = ob[6]; o1.w = ob[7];
    *(ushort4*)(out + (long)node * 256 + lane * 8) = o0;
    *(ushort4*)(out + (long)node * 256 + lane * 8 + 4) = o1;
}

// ---------- GEMM v4: faithful port of the HW-verified m93/m97 ladder structure ----------
template <int STATS>
__global__ __launch_bounds__(256) void gemm_big(const u16* __restrict__ A, const u16* __restrict__ BT,
                                                const float* __restrict__ bias, u16* __restrict__ C,
                                                float* __restrict__ sums, int M) {
    __shared__ u16 As[128 * 64];   // 16 KB
    __shared__ u16 Bs[128 * 64];   // 16 KB
    __shared__ u16 Cs[64 * 136];   // 17 KB transpose tile (+8 pad)
    int tid = threadIdx.x;
    int wave = tid >> 6, lane = tid & 63, l15 = lane & 15, quad = lane >> 4;
    int row0 = blockIdx.x * 128;
    int col0 = blockIdx.y * 128;
    int wr = (wave & 1) * 64, wc = (wave >> 1) * 64;

    floatx4 acc[4][4];
    floatx4 zero = {0.f, 0.f, 0.f, 0.f};
#pragma unroll
    for (int mi = 0; mi < 4; mi++)
#pragma unroll
        for (int ni = 0; ni < 4; ni++) acc[mi][ni] = zero;

    for (int k0 = 0; k0 < 256; k0 += 64) {
#pragma unroll
        for (int c = 0; c < 4; c++) {          // stage A and B tiles: 1024 16B-chunks each
            int id = c * 256 + tid;
            int r = id >> 3, kc = id & 7;
            *(uint4*)(As + r * 64 + kc * 8) =
                *(const uint4*)(A + (long)min(row0 + r, M - 1) * 256 + k0 + kc * 8);
            *(uint4*)(Bs + r * 64 + kc * 8) =
                *(const uint4*)(BT + (long)(col0 + r) * 256 + k0 + kc * 8);
        }
        __syncthreads();
#pragma unroll
        for (int kk = 0; kk < 64; kk += 32) {
            short8 am[4], bn[4];
#pragma unroll
            for (int i = 0; i < 4; i++) {
                am[i] = *(const short8*)(As + (wr + i * 16 + l15) * 64 + kk + quad * 8);
                bn[i] = *(const short8*)(Bs + (wc + i * 16 + l15) * 64 + kk + quad * 8);
            }
#pragma unroll
            for (int mi = 0; mi < 4; mi++)
#pragma unroll
                for (int ni = 0; ni < 4; ni++)
                    acc[mi][ni] = __builtin_amdgcn_mfma_f32_16x16x32_bf16(am[mi], bn[ni], acc[mi][ni], 0, 0, 0);
        }
        __syncthreads();
    }

    // ---- epilogue: bias (+ BN column stats), then coalesced store via Cs transpose ----
    float s[4], s2[4];
    if (STATS) {
#pragma unroll
        for (int ni = 0; ni < 4; ni++) { s[ni] = 0.f; s2[ni] = 0.f; }
    }
#pragma unroll
    for (int ni = 0; ni < 4; ni++) {
        int gcol = col0 + wc + ni * 16 + l15;
        float bv = bias[gcol];
#pragma unroll
        for (int mi = 0; mi < 4; mi++)
#pragma unroll
            for (int r = 0; r < 4; r++) {
                float v = acc[mi][ni][r] + bv;
                acc[mi][ni][r] = v;
                if (STATS) {
                    int grow = row0 + wr + mi * 16 + quad * 4 + r;
                    if (grow < M) { s[ni] += v; s2[ni] = fmaf(v, v, s2[ni]); }
                }
            }
    }
    if (STATS) {
#pragma unroll
        for (int ni = 0; ni < 4; ni++) {
            float a = s[ni], b = s2[ni];
            a += __shfl_xor(a, 16, 64); a += __shfl_xor(a, 32, 64);
            b += __shfl_xor(b, 16, 64); b += __shfl_xor(b, 32, 64);
            if (quad == 0) {
                int gcol = col0 + wc + ni * 16 + l15;
                unsafeAtomicAdd(&sums[gcol], a);
                unsafeAtomicAdd(&sums[256 + gcol], b);
            }
        }
    }
    // two 64-row halves: waves with (wave&1)==h own rows h*64..h*64+63
#pragma unroll
    for (int h = 0; h < 2; h++) {
        __syncthreads();
        if ((wave & 1) == h) {
#pragma unroll
            for (int mi = 0; mi < 4; mi++)
#pragma unroll
                for (int ni = 0; ni < 4; ni++)
#pragma unroll
                    for (int r = 0; r < 4; r++)
                        Cs[(mi * 16 + quad * 4 + r) * 136 + wc + ni * 16 + l15] = f2b(acc[mi][ni][r]);
        }
        __syncthreads();
        {   // thread t: row t>>2, 64B chunk t&3 -> full-sector stores
            int r = tid >> 2, ch = tid & 3;
            int grow = row0 + h * 64 + r;
            if (grow < M) {
                const u16* src = Cs + r * 136 + ch * 32;
                u16* dst = C + (long)grow * 256 + col0 + ch * 32;
                uint4 v0 = *(const uint4*)(src);
                uint4 v1 = *(const uint4*)(src + 8);
                uint4 v2 = *(const uint4*)(src + 16);
                uint4 v3 = *(const uint4*)(src + 24);
                *(uint4*)(dst) = v0;
                *(uint4*)(dst + 8) = v1;
                *(uint4*)(dst + 16) = v2;
                *(uint4*)(dst + 24) = v3;
            }
        }
    }
}

// ---------- BN coefficients: scale/shift per column ----------
__global__ __launch_bounds__(256) void bn_coef(const float* __restrict__ sums, const float* __restrict__ gamma,
                                               const float* __restrict__ beta, float* __restrict__ coef, int N) {
    int c = threadIdx.x;
    float invN = 1.0f / (float)N;
    float mean = sums[c] * invN;
    float var = sums[256 + c] * invN - mean * mean;
    float s = gamma[c] * rsqrtf(var + 1e-5f);
    coef[c] = s;
    coef[256 + c] = beta[c] - mean * s;
}

// ---------- predictor v7-split: same per-wave structure; qoff = block offset ----------
// Split into two half-grid launches so predictor (~30us/half) vacates the rocprof top-5,
// exposing aggregate2/gemm_big true durations. Per-block work identical to v7.
__global__ __launch_bounds__(512, 2) void predictor(const u16* __restrict__ h2b, const int* __restrict__ e0,
                                                    const int* __restrict__ e1, const u16* __restrict__ pW1T,
                                                    const float* __restrict__ pb1, const float* __restrict__ pW2,
                                                    const float* __restrict__ pb2, float* __restrict__ out,
                                                    int Q, int qoff) {
    __shared__ u16 Bs[2][32 * 256];   // 2 x 16 KB double buffer
    int tid = threadIdx.x;
    int wave = tid >> 6, lane = tid & 63, l15 = lane & 15, quad = lane >> 4;

    // async stage of 32 weight rows (phase p) into buf; XOR swizzle folded into source address
    auto stage = [&](int p, u16* buf) {
#pragma unroll
        for (int i = 0; i < 2; i++) {
            int m = wave * 2 + i;                 // 1 KB chunk, 16 chunks = 16 KB
            int nl = m * 2 + (lane >> 5);         // local n row 0..31
            int cl = lane & 31;                   // swizzled 16B slot
            int cs = cl ^ (nl & 7);               // source chunk
            const u16* g = pW1T + (long)(p * 32 + nl) * 256 + cs * 8;
            gld_lds16(g, buf + m * 512);          // lane writes at +lane*16B
        }
    };

    stage(0, Bs[0]);   // in flight under the z-gathers

    int q0 = (qoff + blockIdx.x) * 256;
    short8 za[2][8];
#pragma unroll
    for (int mt = 0; mt < 2; mt++) {
        int q = min(q0 + wave * 32 + mt * 16 + l15, Q - 1);
        long u = (long)e0[q] * 256, v = (long)e1[q] * 256;
#pragma unroll
        for (int ki = 0; ki < 8; ki++) {
            uint4 a = *(const uint4*)(h2b + u + ki * 32 + quad * 8);
            uint4 b = *(const uint4*)(h2b + v + ki * 32 + quad * 8);
            uint4 z;
            z.x = pkmul(a.x, b.x);
            z.y = pkmul(a.y, b.y);
            z.z = pkmul(a.z, b.z);
            z.w = pkmul(a.w, b.w);
            za[mt][ki] = *(short8*)&z;
        }
    }
    float rs[2][4] = {{0.f, 0.f, 0.f, 0.f}, {0.f, 0.f, 0.f, 0.f}};
    floatx4 zero = {0.f, 0.f, 0.f, 0.f};

#pragma unroll
    for (int p = 0; p < 8; p++) {
        if (p < 7) {
            stage(p + 1, Bs[(p + 1) & 1]);
            asm volatile("s_waitcnt vmcnt(2)" ::: "memory");
        } else {
            asm volatile("s_waitcnt vmcnt(0)" ::: "memory");
        }
        __builtin_amdgcn_s_barrier();             // buf[p&1] globally ready
        const u16* buf = Bs[p & 1];
        float bb[2], w2[2];
#pragma unroll
        for (int nt = 0; nt < 2; nt++) {
            int col = p * 32 + nt * 16 + l15;
            bb[nt] = pb1[col];
            w2[nt] = pW2[col];
        }
        floatx4 acc[2][2];
#pragma unroll
        for (int mt = 0; mt < 2; mt++) { acc[mt][0] = zero; acc[mt][1] = zero; }
        __builtin_amdgcn_s_setprio(1);
#pragma unroll
        for (int ki = 0; ki < 8; ki++) {
#pragma unroll
            for (int nt = 0; nt < 2; nt++) {
                int nl = nt * 16 + l15;
                int cs = (ki * 4 + quad) ^ (nl & 7);
                short8 b = *(const short8*)(buf + nl * 256 + cs * 8);
#pragma unroll
                for (int mt = 0; mt < 2; mt++)
                    acc[mt][nt] = __builtin_amdgcn_mfma_f32_16x16x32_bf16(za[mt][ki], b, acc[mt][nt], 0, 0, 0);
            }
        }
        __builtin_amdgcn_s_setprio(0);
        if (p < 7) __builtin_amdgcn_s_barrier();  // all waves done reading buf[p&1]
        // fold this phase's 32 cols into rs (register-only, overlaps next stage's flight)
#pragma unroll
        for (int nt = 0; nt < 2; nt++)
#pragma unroll
            for (int mt = 0; mt < 2; mt++)
#pragma unroll
                for (int r = 0; r < 4; r++)
                    rs[mt][r] = fmaf(fmaxf(acc[mt][nt][r] + bb[nt], 0.f), w2[nt], rs[mt][r]);
    }
    // reduce across the 16 col-lanes
#pragma unroll
    for (int m = 1; m < 16; m <<= 1)
#pragma unroll
        for (int mt = 0; mt < 2; mt++)
#pragma unroll
            for (int r = 0; r < 4; r++)
                rs[mt][r] += __shfl_xor(rs[mt][r], m, 64);
    if (l15 == 0) {
        float b2v = pb2[0];
#pragma unroll
        for (int mt = 0; mt < 2; mt++)
#pragma unroll
            for (int r = 0; r < 4; r++) {
                int qq = q0 + wave * 32 + mt * 16 + quad * 4 + r;
                if (qq < Q) out[qq] = 1.0f / (1.0f + __expf(-(rs[mt][r] + b2v)));
            }
    }
}

extern "C" void kernel_launch(void* const* d_in, const int* in_sizes, int n_in,
                              void* d_out, int out_size, void* d_ws, size_t ws_size,
                              hipStream_t stream) {
    const float* x      = (const float*)d_in[0];
    const int*   adj_row= (const int*)d_in[1];
    const int*   adj_col= (const int*)d_in[2];
    const int*   edges  = (const int*)d_in[3];
    const float* emb    = (const float*)d_in[4];
    const float* W1     = (const float*)d_in[5];
    const float* b1     = (const float*)d_in[6];
    const float* W2     = (const float*)d_in[7];
    const float* b2     = (const float*)d_in[8];
    const float* gamma  = (const float*)d_in[9];
    const float* beta   = (const float*)d_in[10];
    const float* pW1    = (const float*)d_in[11];
    const float* pb1    = (const float*)d_in[12];
    const float* pW2    = (const float*)d_in[13];
    const float* pb2    = (const float*)d_in[14];
    float* out = (float*)d_out;

    int N = in_sizes[0] / 128;
    int E = in_sizes[1];
    int Q = in_sizes[3] / 2;

    char* ws = (char*)d_ws;
    size_t off = 0;
    auto alloc = [&](size_t bytes) -> char* {
        char* p = ws + off;
        off += (bytes + 255) & ~(size_t)255;
        return p;
    };
    // --- contiguous zero-init region: deg_cnt | cursor | sums | gcur (ONE memset) ---
    size_t npad = ((size_t)N * 4 + 255) & ~(size_t)255;
    int*   deg_cnt = (int*)alloc((size_t)N * 4);
    int*   cursor  = (int*)alloc((size_t)N * 4);
    float* sums    = (float*)alloc(512 * 4);
    int*   gcur    = (int*)alloc(4);
    size_t zspan   = npad * 2 + 2048 + 256;
    // --- rest ---
    int*   offs    = (int*)alloc((size_t)N * 4);
    float* dinv    = (float*)alloc((size_t)N * 4);
    int*   scol    = (int*)alloc((size_t)E * 4);
    float* coef    = (float*)alloc(512 * 4);
    u16*   WT      = (u16*)alloc((size_t)3 * 65536 * 2);
    u16*   bufA    = (u16*)alloc((size_t)N * 256 * 2);
    u16*   bufB    = (u16*)alloc((size_t)N * 256 * 2);
    u16*   bufC    = (u16*)alloc((size_t)N * 256 * 2);

    hipMemsetAsync(deg_cnt, 0, zspan, stream);

    int eb  = (E + 255) / 256;
    int NB  = (N + 255) / 256;
    int nb4 = (N * 64 + 255) / 256;
    int ab  = (N + 7) / 8;
    dim3 gemmGrid((N + 127) / 128, 2);

    count_deg<<<eb, 256, 0, stream>>>(adj_row, deg_cnt, E);
    alloc_offs<<<NB, 256, 0, stream>>>(deg_cnt, offs, dinv, gcur, N);
    sort_edges<<<eb, 256, 0, stream>>>(adj_row, adj_col, offs, cursor, scol, E);
    prep_wh<<<768 + nb4, 256, 0, stream>>>(W1, W2, pW1, WT, emb, x, bufA, N);

    // conv1 (commuted): h1 = agg(h0) @ W1 + b1, with fused BN column stats
    aggregate2<0><<<ab, 256, 0, stream>>>(bufA, offs, deg_cnt, scol, dinv, nullptr, bufB, N);
    gemm_big<1><<<gemmGrid, 256, 0, stream>>>(bufB, WT, b1, bufC, sums, N);
    bn_coef<<<1, 256, 0, stream>>>(sums, gamma, beta, coef, N);
    // conv2 (commuted): h2 = agg(relu(bn(h1))) @ W2 + b2, BN+ReLU fused into gather
    aggregate2<1><<<ab, 256, 0, stream>>>(bufC, offs, deg_cnt, scol, dinv, coef, bufB, N);
    gemm_big<0><<<gemmGrid, 256, 0, stream>>>(bufB, WT + 65536, b2, bufC, nullptr, N);
    // link predictor: two half-grid launches (diagnostic split; see header comment)
    int PB = (Q + 255) / 256;
    int PB1 = PB / 2;
    predictor<<<PB1, 512, 0, stream>>>(bufC, edges, edges + Q,
                                       WT + 131072, pb1, pW2, pb2, out, Q, 0);
    predictor<<<PB - PB1, 512, 0, stream>>>(bufC, edges, edges + Q,
                                            WT + 131072, pb1, pW2, pb2, out, Q, PB1);
}

// Round 9
// 395.644 us; speedup vs baseline: 1.0040x; 1.0040x over previous
//
#include <hip/hip_runtime.h>

typedef unsigned short u16;
typedef unsigned int u32;
typedef __attribute__((ext_vector_type(8))) short short8;
typedef __attribute__((ext_vector_type(4))) float floatx4;

// ---------- bf16 helpers ----------
__device__ __forceinline__ float b2f(u32 bits) { union { u32 u; float f; } c; c.u = bits << 16; return c.f; }
__device__ __forceinline__ float b2f_lo(u32 w) { union { u32 u; float f; } c; c.u = w << 16; return c.f; }
__device__ __forceinline__ float b2f_hi(u32 w) { union { u32 u; float f; } c; c.u = w & 0xFFFF0000u; return c.f; }
__device__ __forceinline__ u16 f2b(float f) {
    union { float f; u32 u; } c; c.f = f;
    u32 u = c.u;
    return (u16)((u + 0x7FFFu + ((u >> 16) & 1u)) >> 16);   // RNE
}
// packed bf16 mul, round-half-up (bias ~2^-16 rel)
__device__ __forceinline__ u32 pkmul(u32 a, u32 b) {
    union { u32 u; float f; } alo, ahi, blo, bhi, rlo, rhi;
    alo.u = a << 16; ahi.u = a & 0xFFFF0000u;
    blo.u = b << 16; bhi.u = b & 0xFFFF0000u;
    rlo.f = alo.f * blo.f; rhi.f = ahi.f * bhi.f;
    u32 lo = rlo.u + 0x8000u, hi = rhi.u + 0x8000u;
    return __builtin_amdgcn_perm(hi, lo, 0x07060302u);
}
// async global->LDS, 16B per lane; lds base must be wave-uniform
__device__ __forceinline__ void gld_lds16(const u16* g, u16* l) {
    __builtin_amdgcn_global_load_lds((const __attribute__((address_space(1))) u32*)g,
                                     (__attribute__((address_space(3))) u32*)l, 16, 0, 0);
}

// ---------- graph prep ----------
__global__ __launch_bounds__(256) void count_deg(const int* __restrict__ row, int* __restrict__ cnt, int E) {
    int e = blockIdx.x * 256 + threadIdx.x;
    if (e < E) atomicAdd(&cnt[row[e]], 1);
}

// CSR segment allocation WITHOUT ordered scan: wave-prefix + 1 atomic bump per wave.
__global__ __launch_bounds__(256) void alloc_offs(const int* __restrict__ cnt, int* __restrict__ offs,
                                                  float* __restrict__ dinv, int* __restrict__ gcur, int N) {
    int i = blockIdx.x * 256 + threadIdx.x;
    int lane = threadIdx.x & 63;
    int c = (i < N) ? cnt[i] : 0;
    int sc = c;
#pragma unroll
    for (int o = 1; o < 64; o <<= 1) {
        int u = __shfl_up(sc, o, 64);
        if (lane >= o) sc += u;
    }
    int ex = sc - c;                       // exclusive prefix within wave
    int total = __shfl(sc, 63, 64);        // wave total
    int base = 0;
    if (lane == 63) base = atomicAdd(gcur, total);
    base = __shfl(base, 63, 64);
    if (i < N) {
        offs[i] = base + ex;
        dinv[i] = rsqrtf((float)c + 1.0f);
    }
}

__global__ __launch_bounds__(256) void sort_edges(const int* __restrict__ row, const int* __restrict__ col,
                                                  const int* __restrict__ offs, int* __restrict__ cursor,
                                                  int* __restrict__ scol, int E) {
    int e = blockIdx.x * 256 + threadIdx.x;
    if (e < E) {
        int r = row[e];
        int p = offs[r] + atomicAdd(&cursor[r], 1);
        scol[p] = col[e];
    }
}

// ---------- fused weight prep + h0 concat (one launch) ----------
__global__ __launch_bounds__(256) void prep_wh(const float* __restrict__ W1, const float* __restrict__ W2,
                                               const float* __restrict__ pW1, u16* __restrict__ WT,
                                               const float* __restrict__ emb, const float* __restrict__ x,
                                               u16* __restrict__ h0b, int N) {
    int b = blockIdx.x;
    if (b < 768) {
        int tid = b * 256 + threadIdx.x;
        int which = tid >> 16, id = tid & 65535;
        int n = id >> 8, k = id & 255;
        const float* W = (which == 0) ? W1 : ((which == 1) ? W2 : pW1);
        WT[tid] = f2b(W[k * 256 + n]);
    } else {
        int t = (b - 768) * 256 + threadIdx.x;
        long base = (long)t * 4;
        if (base >= (long)N * 256) return;
        int i = (int)(base >> 8), k = (int)(base & 255);
        const float* src = (k < 128) ? (emb + (long)i * 128 + k) : (x + (long)i * 128 + (k - 128));
        float4 v = *(const float4*)src;
        ushort4 o;
        o.x = f2b(v.x); o.y = f2b(v.y); o.z = f2b(v.z); o.w = f2b(v.w);
        *(ushort4*)(h0b + base) = o;
    }
}

// ---------- aggregation: 1 node per half-wave (32 lanes x uint4 = full 512B row) ----------
template <int FUSED_BN>
__global__ __launch_bounds__(256) void aggregate2(const u16* __restrict__ h, const int* __restrict__ offs,
                                                  const int* __restrict__ cnt, const int* __restrict__ scol,
                                                  const float* __restrict__ dinv, const float* __restrict__ coef,
                                                  u16* __restrict__ out, int N) {
    int hw = threadIdx.x >> 5, lane = threadIdx.x & 31;
    int node = blockIdx.x * 8 + hw;
    if (node >= N) return;
    float sc[8], sh[8];
    if (FUSED_BN) {
#pragma unroll
        for (int i = 0; i < 8; i++) { sc[i] = coef[lane * 8 + i]; sh[i] = coef[256 + lane * 8 + i]; }
    }
    float a[8];
#pragma unroll
    for (int i = 0; i < 8; i++) a[i] = 0.f;

    auto rowAcc = [&](uint4 u, float d) {
        float f[8];
        f[0] = b2f_lo(u.x); f[1] = b2f_hi(u.x);
        f[2] = b2f_lo(u.y); f[3] = b2f_hi(u.y);
        f[4] = b2f_lo(u.z); f[5] = b2f_hi(u.z);
        f[6] = b2f_lo(u.w); f[7] = b2f_hi(u.w);
#pragma unroll
        for (int i = 0; i < 8; i++) {
            float v = f[i];
            if (FUSED_BN) v = fmaxf(fmaf(v, sc[i], sh[i]), 0.f);
            a[i] = fmaf(v, d, a[i]);
        }
    };
    int beg = offs[node], end = beg + cnt[node];
    int j = beg;
    for (; j + 3 < end; j += 4) {
        int c0 = scol[j], c1 = scol[j + 1], c2 = scol[j + 2], c3 = scol[j + 3];
        float d0 = dinv[c0], d1 = dinv[c1], d2 = dinv[c2], d3 = dinv[c3];
        uint4 v0 = *(const uint4*)(h + (long)c0 * 256 + lane * 8);
        uint4 v1 = *(const uint4*)(h + (long)c1 * 256 + lane * 8);
        uint4 v2 = *(const uint4*)(h + (long)c2 * 256 + lane * 8);
        uint4 v3 = *(const uint4*)(h + (long)c3 * 256 + lane * 8);
        rowAcc(v0, d0); rowAcc(v1, d1); rowAcc(v2, d2); rowAcc(v3, d3);
    }
    for (; j < end; j++) {
        int c0 = scol[j];
        float d0 = dinv[c0];
        uint4 v0 = *(const uint4*)(h + (long)c0 * 256 + lane * 8);
        rowAcc(v0, d0);
    }
    float di = dinv[node];
    {
        uint4 u = *(const uint4*)(h + (long)node * 256 + lane * 8);
        rowAcc(u, di);   // self term with weight di (total = sum + di*self)
    }
    u16 ob[8];
#pragma unroll
    for (int i = 0; i < 8; i++) ob[i] = f2b(di * a[i]);
    ushort4 o0, o1;
    o0.x = ob[0]; o0.y = ob[1]; o0.z = ob[2]; o0.w = ob[3];
    o1.x = ob[4]; o1.y = ob[5]; o1.z = ob[6]; o1.w = ob[7];
    *(ushort4*)(out + (long)node * 256 + lane * 8) = o0;
    *(ushort4*)(out + (long)node * 256 + lane * 8 + 4) = o1;
}

// ---------- GEMM v5: BK=32, 8 phases, 2-deep gld_lds double-buffer, counted vmcnt(4) ----------
// LDS 32 KB total (2 bufs x (A 8K + B 8K)); Cs (17KB) ALIASES the staging space in the
// epilogue (staging dead after K-loop; epilogue barriers make reuse safe). 4 blocks/CU
// -> the 782-block grid fits ONE occupancy wave (round-8 PMC: 49KB LDS -> 3/CU -> 1.02
// waves -> ~2x runtime; MfmaUtil 4.4%, Occ 14%). Source-chunk XOR swizzle kills the
// 16-way ds_read bank conflict of the old 128B-row layout.
template <int STATS>
__global__ __launch_bounds__(256) void gemm_big(const u16* __restrict__ A, const u16* __restrict__ BT,
                                                const float* __restrict__ bias, u16* __restrict__ C,
                                                float* __restrict__ sums, int M) {
    __shared__ u16 lds[16384];   // 32 KB: buf b at b*8192 (A 4096 u16 | B 4096 u16)
    int tid = threadIdx.x;
    int wave = tid >> 6, lane = tid & 63, l15 = lane & 15, quad = lane >> 4;
    int row0 = blockIdx.x * 128;
    int col0 = blockIdx.y * 128;
    int wr = (wave & 1) * 64, wc = (wave >> 1) * 64;

    // stage K-phase p (32 cols) into buffer b: 512 A-chunks + 512 B-chunks of 16B.
    // LDS slot (row, cl) <- global chunk cl ^ ((row>>1)&3)  [read applies same XOR]
    auto stage = [&](int p, int b) {
        int k0 = p * 32;
        u16* dstA = lds + b * 8192;
        u16* dstB = dstA + 4096;
#pragma unroll
        for (int i = 0; i < 2; i++) {
            int g = wave * 2 + i;                   // 64-chunk group 0..7
            int c = g * 64 + lane;                  // chunk 0..511
            int r = c >> 2, cl = c & 3;
            int cs = cl ^ ((r >> 1) & 3);           // pre-swizzled source chunk
            gld_lds16(A + (long)min(row0 + r, M - 1) * 256 + k0 + cs * 8, dstA + g * 512);
            gld_lds16(BT + (long)(col0 + r) * 256 + k0 + cs * 8, dstB + g * 512);
        }
    };

    floatx4 acc[4][4];
    floatx4 zero = {0.f, 0.f, 0.f, 0.f};
#pragma unroll
    for (int mi = 0; mi < 4; mi++)
#pragma unroll
        for (int ni = 0; ni < 4; ni++) acc[mi][ni] = zero;

    stage(0, 0);
#pragma unroll
    for (int p = 0; p < 8; p++) {
        if (p < 7) {
            stage(p + 1, (p + 1) & 1);
            asm volatile("s_waitcnt vmcnt(4)" ::: "memory");   // drain stage(p), keep stage(p+1) in flight
        } else {
            asm volatile("s_waitcnt vmcnt(0)" ::: "memory");
        }
        __builtin_amdgcn_s_barrier();            // buf[p&1] globally ready
        const u16* As = lds + (p & 1) * 8192;
        const u16* Bs = As + 4096;
        short8 am[4], bn[4];
#pragma unroll
        for (int i = 0; i < 4; i++) {
            int ra = wr + i * 16 + l15;
            int rb = wc + i * 16 + l15;
            am[i] = *(const short8*)(As + ra * 32 + ((quad ^ ((ra >> 1) & 3)) * 8));
            bn[i] = *(const short8*)(Bs + rb * 32 + ((quad ^ ((rb >> 1) & 3)) * 8));
        }
        __builtin_amdgcn_s_setprio(1);
#pragma unroll
        for (int mi = 0; mi < 4; mi++)
#pragma unroll
            for (int ni = 0; ni < 4; ni++)
                acc[mi][ni] = __builtin_amdgcn_mfma_f32_16x16x32_bf16(am[mi], bn[ni], acc[mi][ni], 0, 0, 0);
        __builtin_amdgcn_s_setprio(0);
        if (p < 7) __builtin_amdgcn_s_barrier(); // all waves done reading buf[p&1] before overwrite
    }

    // ---- epilogue: bias (+ BN column stats), then coalesced store via Cs transpose ----
    u16* Cs = lds;   // 64x136 u16 = 8704, aliases staging (dead; barriers below guard reuse)
    float s[4], s2[4];
    if (STATS) {
#pragma unroll
        for (int ni = 0; ni < 4; ni++) { s[ni] = 0.f; s2[ni] = 0.f; }
    }
#pragma unroll
    for (int ni = 0; ni < 4; ni++) {
        int gcol = col0 + wc + ni * 16 + l15;
        float bv = bias[gcol];
#pragma unroll
        for (int mi = 0; mi < 4; mi++)
#pragma unroll
            for (int r = 0; r < 4; r++) {
                float v = acc[mi][ni][r] + bv;
                acc[mi][ni][r] = v;
                if (STATS) {
                    int grow = row0 + wr + mi * 16 + quad * 4 + r;
                    if (grow < M) { s[ni] += v; s2[ni] = fmaf(v, v, s2[ni]); }
                }
            }
    }
    if (STATS) {
#pragma unroll
        for (int ni = 0; ni < 4; ni++) {
            float a = s[ni], b = s2[ni];
            a += __shfl_xor(a, 16, 64); a += __shfl_xor(a, 32, 64);
            b += __shfl_xor(b, 16, 64); b += __shfl_xor(b, 32, 64);
            if (quad == 0) {
                int gcol = col0 + wc + ni * 16 + l15;
                unsafeAtomicAdd(&sums[gcol], a);
                unsafeAtomicAdd(&sums[256 + gcol], b);
            }
        }
    }
    // two 64-row halves: waves with (wave&1)==h own rows h*64..h*64+63
#pragma unroll
    for (int h = 0; h < 2; h++) {
        __syncthreads();
        if ((wave & 1) == h) {
#pragma unroll
            for (int mi = 0; mi < 4; mi++)
#pragma unroll
                for (int ni = 0; ni < 4; ni++)
#pragma unroll
                    for (int r = 0; r < 4; r++)
                        Cs[(mi * 16 + quad * 4 + r) * 136 + wc + ni * 16 + l15] = f2b(acc[mi][ni][r]);
        }
        __syncthreads();
        {   // thread t: row t>>2, 64B chunk t&3 -> full-sector stores
            int r = tid >> 2, ch = tid & 3;
            int grow = row0 + h * 64 + r;
            if (grow < M) {
                const u16* src = Cs + r * 136 + ch * 32;
                u16* dst = C + (long)grow * 256 + col0 + ch * 32;
                uint4 v0 = *(const uint4*)(src);
                uint4 v1 = *(const uint4*)(src + 8);
                uint4 v2 = *(const uint4*)(src + 16);
                uint4 v3 = *(const uint4*)(src + 24);
                *(uint4*)(dst) = v0;
                *(uint4*)(dst + 8) = v1;
                *(uint4*)(dst + 16) = v2;
                *(uint4*)(dst + 24) = v3;
            }
        }
    }
}

// ---------- BN coefficients: scale/shift per column ----------
__global__ __launch_bounds__(256) void bn_coef(const float* __restrict__ sums, const float* __restrict__ gamma,
                                               const float* __restrict__ beta, float* __restrict__ coef, int N) {
    int c = threadIdx.x;
    float invN = 1.0f / (float)N;
    float mean = sums[c] * invN;
    float var = sums[256 + c] * invN - mean * mean;
    float s = gamma[c] * rsqrtf(var + 1e-5f);
    coef[c] = s;
    coef[256 + c] = beta[c] - mean * s;
}

// ---------- predictor v7-split: same per-wave structure; qoff = block offset ----------
__global__ __launch_bounds__(512, 2) void predictor(const u16* __restrict__ h2b, const int* __restrict__ e0,
                                                    const int* __restrict__ e1, const u16* __restrict__ pW1T,
                                                    const float* __restrict__ pb1, const float* __restrict__ pW2,
                                                    const float* __restrict__ pb2, float* __restrict__ out,
                                                    int Q, int qoff) {
    __shared__ u16 Bs[2][32 * 256];   // 2 x 16 KB double buffer
    int tid = threadIdx.x;
    int wave = tid >> 6, lane = tid & 63, l15 = lane & 15, quad = lane >> 4;

    // async stage of 32 weight rows (phase p) into buf; XOR swizzle folded into source address
    auto stage = [&](int p, u16* buf) {
#pragma unroll
        for (int i = 0; i < 2; i++) {
            int m = wave * 2 + i;                 // 1 KB chunk, 16 chunks = 16 KB
            int nl = m * 2 + (lane >> 5);         // local n row 0..31
            int cl = lane & 31;                   // swizzled 16B slot
            int cs = cl ^ (nl & 7);               // source chunk
            const u16* g = pW1T + (long)(p * 32 + nl) * 256 + cs * 8;
            gld_lds16(g, buf + m * 512);          // lane writes at +lane*16B
        }
    };

    stage(0, Bs[0]);   // in flight under the z-gathers

    int q0 = (qoff + blockIdx.x) * 256;
    short8 za[2][8];
#pragma unroll
    for (int mt = 0; mt < 2; mt++) {
        int q = min(q0 + wave * 32 + mt * 16 + l15, Q - 1);
        long u = (long)e0[q] * 256, v = (long)e1[q] * 256;
#pragma unroll
        for (int ki = 0; ki < 8; ki++) {
            uint4 a = *(const uint4*)(h2b + u + ki * 32 + quad * 8);
            uint4 b = *(const uint4*)(h2b + v + ki * 32 + quad * 8);
            uint4 z;
            z.x = pkmul(a.x, b.x);
            z.y = pkmul(a.y, b.y);
            z.z = pkmul(a.z, b.z);
            z.w = pkmul(a.w, b.w);
            za[mt][ki] = *(short8*)&z;
        }
    }
    float rs[2][4] = {{0.f, 0.f, 0.f, 0.f}, {0.f, 0.f, 0.f, 0.f}};
    floatx4 zero = {0.f, 0.f, 0.f, 0.f};

#pragma unroll
    for (int p = 0; p < 8; p++) {
        if (p < 7) {
            stage(p + 1, Bs[(p + 1) & 1]);
            asm volatile("s_waitcnt vmcnt(2)" ::: "memory");
        } else {
            asm volatile("s_waitcnt vmcnt(0)" ::: "memory");
        }
        __builtin_amdgcn_s_barrier();             // buf[p&1] globally ready
        const u16* buf = Bs[p & 1];
        float bb[2], w2[2];
#pragma unroll
        for (int nt = 0; nt < 2; nt++) {
            int col = p * 32 + nt * 16 + l15;
            bb[nt] = pb1[col];
            w2[nt] = pW2[col];
        }
        floatx4 acc[2][2];
#pragma unroll
        for (int mt = 0; mt < 2; mt++) { acc[mt][0] = zero; acc[mt][1] = zero; }
        __builtin_amdgcn_s_setprio(1);
#pragma unroll
        for (int ki = 0; ki < 8; ki++) {
#pragma unroll
            for (int nt = 0; nt < 2; nt++) {
                int nl = nt * 16 + l15;
                int cs = (ki * 4 + quad) ^ (nl & 7);
                short8 b = *(const short8*)(buf + nl * 256 + cs * 8);
#pragma unroll
                for (int mt = 0; mt < 2; mt++)
                    acc[mt][nt] = __builtin_amdgcn_mfma_f32_16x16x32_bf16(za[mt][ki], b, acc[mt][nt], 0, 0, 0);
            }
        }
        __builtin_amdgcn_s_setprio(0);
        if (p < 7) __builtin_amdgcn_s_barrier();  // all waves done reading buf[p&1]
        // fold this phase's 32 cols into rs (register-only, overlaps next stage's flight)
#pragma unroll
        for (int nt = 0; nt < 2; nt++)
#pragma unroll
            for (int mt = 0; mt < 2; mt++)
#pragma unroll
                for (int r = 0; r < 4; r++)
                    rs[mt][r] = fmaf(fmaxf(acc[mt][nt][r] + bb[nt], 0.f), w2[nt], rs[mt][r]);
    }
    // reduce across the 16 col-lanes
#pragma unroll
    for (int m = 1; m < 16; m <<= 1)
#pragma unroll
        for (int mt = 0; mt < 2; mt++)
#pragma unroll
            for (int r = 0; r < 4; r++)
                rs[mt][r] += __shfl_xor(rs[mt][r], m, 64);
    if (l15 == 0) {
        float b2v = pb2[0];
#pragma unroll
        for (int mt = 0; mt < 2; mt++)
#pragma unroll
            for (int r = 0; r < 4; r++) {
                int qq = q0 + wave * 32 + mt * 16 + quad * 4 + r;
                if (qq < Q) out[qq] = 1.0f / (1.0f + __expf(-(rs[mt][r] + b2v)));
            }
    }
}

extern "C" void kernel_launch(void* const* d_in, const int* in_sizes, int n_in,
                              void* d_out, int out_size, void* d_ws, size_t ws_size,
                              hipStream_t stream) {
    const float* x      = (const float*)d_in[0];
    const int*   adj_row= (const int*)d_in[1];
    const int*   adj_col= (const int*)d_in[2];
    const int*   edges  = (const int*)d_in[3];
    const float* emb    = (const float*)d_in[4];
    const float* W1     = (const float*)d_in[5];
    const float* b1     = (const float*)d_in[6];
    const float* W2     = (const float*)d_in[7];
    const float* b2     = (const float*)d_in[8];
    const float* gamma  = (const float*)d_in[9];
    const float* beta   = (const float*)d_in[10];
    const float* pW1    = (const float*)d_in[11];
    const float* pb1    = (const float*)d_in[12];
    const float* pW2    = (const float*)d_in[13];
    const float* pb2    = (const float*)d_in[14];
    float* out = (float*)d_out;

    int N = in_sizes[0] / 128;
    int E = in_sizes[1];
    int Q = in_sizes[3] / 2;

    char* ws = (char*)d_ws;
    size_t off = 0;
    auto alloc = [&](size_t bytes) -> char* {
        char* p = ws + off;
        off += (bytes + 255) & ~(size_t)255;
        return p;
    };
    // --- contiguous zero-init region: deg_cnt | cursor | sums | gcur (ONE memset) ---
    size_t npad = ((size_t)N * 4 + 255) & ~(size_t)255;
    int*   deg_cnt = (int*)alloc((size_t)N * 4);
    int*   cursor  = (int*)alloc((size_t)N * 4);
    float* sums    = (float*)alloc(512 * 4);
    int*   gcur    = (int*)alloc(4);
    size_t zspan   = npad * 2 + 2048 + 256;
    // --- rest ---
    int*   offs    = (int*)alloc((size_t)N * 4);
    float* dinv    = (float*)alloc((size_t)N * 4);
    int*   scol    = (int*)alloc((size_t)E * 4);
    float* coef    = (float*)alloc(512 * 4);
    u16*   WT      = (u16*)alloc((size_t)3 * 65536 * 2);
    u16*   bufA    = (u16*)alloc((size_t)N * 256 * 2);
    u16*   bufB    = (u16*)alloc((size_t)N * 256 * 2);
    u16*   bufC    = (u16*)alloc((size_t)N * 256 * 2);

    hipMemsetAsync(deg_cnt, 0, zspan, stream);

    int eb  = (E + 255) / 256;
    int NB  = (N + 255) / 256;
    int nb4 = (N * 64 + 255) / 256;
    int ab  = (N + 7) / 8;
    dim3 gemmGrid((N + 127) / 128, 2);

    count_deg<<<eb, 256, 0, stream>>>(adj_row, deg_cnt, E);
    alloc_offs<<<NB, 256, 0, stream>>>(deg_cnt, offs, dinv, gcur, N);
    sort_edges<<<eb, 256, 0, stream>>>(adj_row, adj_col, offs, cursor, scol, E);
    prep_wh<<<768 + nb4, 256, 0, stream>>>(W1, W2, pW1, WT, emb, x, bufA, N);

    // conv1 (commuted): h1 = agg(h0) @ W1 + b1, with fused BN column stats
    aggregate2<0><<<ab, 256, 0, stream>>>(bufA, offs, deg_cnt, scol, dinv, nullptr, bufB, N);
    gemm_big<1><<<gemmGrid, 256, 0, stream>>>(bufB, WT, b1, bufC, sums, N);
    bn_coef<<<1, 256, 0, stream>>>(sums, gamma, beta, coef, N);
    // conv2 (commuted): h2 = agg(relu(bn(h1))) @ W2 + b2, BN+ReLU fused into gather
    aggregate2<1><<<ab, 256, 0, stream>>>(bufC, offs, deg_cnt, scol, dinv, coef, bufB, N);
    gemm_big<0><<<gemmGrid, 256, 0, stream>>>(bufB, WT + 65536, b2, bufC, nullptr, N);
    // link predictor: two half-grid launches (diagnostic split; see round-7 note)
    int PB = (Q + 255) / 256;
    int PB1 = PB / 2;
    predictor<<<PB1, 512, 0, stream>>>(bufC, edges, edges + Q,
                                       WT + 131072, pb1, pW2, pb2, out, Q, 0);
    predictor<<<PB - PB1, 512, 0, stream>>>(bufC, edges, edges + Q,
                                            WT + 131072, pb1, pW2, pb2, out, Q, PB1);
}

// Round 10
// 392.959 us; speedup vs baseline: 1.0108x; 1.0068x over previous
//
#include <hip/hip_runtime.h>

typedef unsigned short u16;
typedef unsigned int u32;
typedef __attribute__((ext_vector_type(8))) short short8;
typedef __attribute__((ext_vector_type(4))) float floatx4;

// ---------- bf16 helpers ----------
__device__ __forceinline__ float b2f(u32 bits) { union { u32 u; float f; } c; c.u = bits << 16; return c.f; }
__device__ __forceinline__ float b2f_lo(u32 w) { union { u32 u; float f; } c; c.u = w << 16; return c.f; }
__device__ __forceinline__ float b2f_hi(u32 w) { union { u32 u; float f; } c; c.u = w & 0xFFFF0000u; return c.f; }
__device__ __forceinline__ u16 f2b(float f) {
    union { float f; u32 u; } c; c.f = f;
    u32 u = c.u;
    return (u16)((u + 0x7FFFu + ((u >> 16) & 1u)) >> 16);   // RNE
}
// packed bf16 mul, round-half-up (bias ~2^-16 rel)
__device__ __forceinline__ u32 pkmul(u32 a, u32 b) {
    union { u32 u; float f; } alo, ahi, blo, bhi, rlo, rhi;
    alo.u = a << 16; ahi.u = a & 0xFFFF0000u;
    blo.u = b << 16; bhi.u = b & 0xFFFF0000u;
    rlo.f = alo.f * blo.f; rhi.f = ahi.f * bhi.f;
    u32 lo = rlo.u + 0x8000u, hi = rhi.u + 0x8000u;
    return __builtin_amdgcn_perm(hi, lo, 0x07060302u);
}
// async global->LDS, 16B per lane; lds base must be wave-uniform
__device__ __forceinline__ void gld_lds16(const u16* g, u16* l) {
    __builtin_amdgcn_global_load_lds((const __attribute__((address_space(1))) u32*)g,
                                     (__attribute__((address_space(3))) u32*)l, 16, 0, 0);
}

// ---------- graph prep ----------
__global__ __launch_bounds__(256) void count_deg(const int* __restrict__ row, int* __restrict__ cnt, int E) {
    int e = blockIdx.x * 256 + threadIdx.x;
    if (e < E) atomicAdd(&cnt[row[e]], 1);
}

// CSR segment allocation WITHOUT ordered scan: wave-prefix + 1 atomic bump per wave.
__global__ __launch_bounds__(256) void alloc_offs(const int* __restrict__ cnt, int* __restrict__ offs,
                                                  float* __restrict__ dinv, int* __restrict__ gcur, int N) {
    int i = blockIdx.x * 256 + threadIdx.x;
    int lane = threadIdx.x & 63;
    int c = (i < N) ? cnt[i] : 0;
    int sc = c;
#pragma unroll
    for (int o = 1; o < 64; o <<= 1) {
        int u = __shfl_up(sc, o, 64);
        if (lane >= o) sc += u;
    }
    int ex = sc - c;                       // exclusive prefix within wave
    int total = __shfl(sc, 63, 64);        // wave total
    int base = 0;
    if (lane == 63) base = atomicAdd(gcur, total);
    base = __shfl(base, 63, 64);
    if (i < N) {
        offs[i] = base + ex;
        dinv[i] = rsqrtf((float)c + 1.0f);
    }
}

__global__ __launch_bounds__(256) void sort_edges(const int* __restrict__ row, const int* __restrict__ col,
                                                  const int* __restrict__ offs, int* __restrict__ cursor,
                                                  int* __restrict__ scol, int E) {
    int e = blockIdx.x * 256 + threadIdx.x;
    if (e < E) {
        int r = row[e];
        int p = offs[r] + atomicAdd(&cursor[r], 1);
        scol[p] = col[e];
    }
}

// ---------- fused weight prep + h0 concat (one launch) ----------
__global__ __launch_bounds__(256) void prep_wh(const float* __restrict__ W1, const float* __restrict__ W2,
                                               const float* __restrict__ pW1, u16* __restrict__ WT,
                                               const float* __restrict__ emb, const float* __restrict__ x,
                                               u16* __restrict__ h0b, int N) {
    int b = blockIdx.x;
    if (b < 768) {
        int tid = b * 256 + threadIdx.x;
        int which = tid >> 16, id = tid & 65535;
        int n = id >> 8, k = id & 255;
        const float* W = (which == 0) ? W1 : ((which == 1) ? W2 : pW1);
        WT[tid] = f2b(W[k * 256 + n]);
    } else {
        int t = (b - 768) * 256 + threadIdx.x;
        long base = (long)t * 4;
        if (base >= (long)N * 256) return;
        int i = (int)(base >> 8), k = (int)(base & 255);
        const float* src = (k < 128) ? (emb + (long)i * 128 + k) : (x + (long)i * 128 + (k - 128));
        float4 v = *(const float4*)src;
        ushort4 o;
        o.x = f2b(v.x); o.y = f2b(v.y); o.z = f2b(v.z); o.w = f2b(v.w);
        *(ushort4*)(h0b + base) = o;
    }
}

// ---------- aggregation: 1 node per half-wave (32 lanes x uint4 = full 512B row) ----------
template <int FUSED_BN>
__global__ __launch_bounds__(256) void aggregate2(const u16* __restrict__ h, const int* __restrict__ offs,
                                                  const int* __restrict__ cnt, const int* __restrict__ scol,
                                                  const float* __restrict__ dinv, const float* __restrict__ coef,
                                                  u16* __restrict__ out, int N) {
    int hw = threadIdx.x >> 5, lane = threadIdx.x & 31;
    int node = blockIdx.x * 8 + hw;
    if (node >= N) return;
    float sc[8], sh[8];
    if (FUSED_BN) {
#pragma unroll
        for (int i = 0; i < 8; i++) { sc[i] = coef[lane * 8 + i]; sh[i] = coef[256 + lane * 8 + i]; }
    }
    float a[8];
#pragma unroll
    for (int i = 0; i < 8; i++) a[i] = 0.f;

    auto rowAcc = [&](uint4 u, float d) {
        float f[8];
        f[0] = b2f_lo(u.x); f[1] = b2f_hi(u.x);
        f[2] = b2f_lo(u.y); f[3] = b2f_hi(u.y);
        f[4] = b2f_lo(u.z); f[5] = b2f_hi(u.z);
        f[6] = b2f_lo(u.w); f[7] = b2f_hi(u.w);
#pragma unroll
        for (int i = 0; i < 8; i++) {
            float v = f[i];
            if (FUSED_BN) v = fmaxf(fmaf(v, sc[i], sh[i]), 0.f);
            a[i] = fmaf(v, d, a[i]);
        }
    };
    int beg = offs[node], end = beg + cnt[node];
    int j = beg;
    for (; j + 3 < end; j += 4) {
        int c0 = scol[j], c1 = scol[j + 1], c2 = scol[j + 2], c3 = scol[j + 3];
        float d0 = dinv[c0], d1 = dinv[c1], d2 = dinv[c2], d3 = dinv[c3];
        uint4 v0 = *(const uint4*)(h + (long)c0 * 256 + lane * 8);
        uint4 v1 = *(const uint4*)(h + (long)c1 * 256 + lane * 8);
        uint4 v2 = *(const uint4*)(h + (long)c2 * 256 + lane * 8);
        uint4 v3 = *(const uint4*)(h + (long)c3 * 256 + lane * 8);
        rowAcc(v0, d0); rowAcc(v1, d1); rowAcc(v2, d2); rowAcc(v3, d3);
    }
    for (; j < end; j++) {
        int c0 = scol[j];
        float d0 = dinv[c0];
        uint4 v0 = *(const uint4*)(h + (long)c0 * 256 + lane * 8);
        rowAcc(v0, d0);
    }
    float di = dinv[node];
    {
        uint4 u = *(const uint4*)(h + (long)node * 256 + lane * 8);
        rowAcc(u, di);   // self term with weight di (total = sum + di*self)
    }
    u16 ob[8];
#pragma unroll
    for (int i = 0; i < 8; i++) ob[i] = f2b(di * a[i]);
    ushort4 o0, o1;
    o0.x = ob[0]; o0.y = ob[1]; o0.z = ob[2]; o0.w = ob[3];
    o1.x = ob[4]; o1.y = ob[5]; o1.z = ob[6]; o1.w = ob[7];
    *(ushort4*)(out + (long)node * 256 + lane * 8) = o0;
    *(ushort4*)(out + (long)node * 256 + lane * 8 + 4) = o1;
}

// ---------- GEMM v6: B-resident LDS (64KB), barrier-free A-streaming main loop ----------
// Shape insight: K=256, N-half=128 -> the whole B half-tile is 64KB. Load it ONCE, then
// NO barriers in the main loop: each wave independently streams A global->reg and MFMAs
// against resident B. (v4/v5 lesson: stage->vmcnt->barrier lockstep at 16-64 MFMAs/phase
// pays a full HBM-latency drain per phase -> 6x above the memory floor.)
// Block: 512 thr / 8 waves; tile 256 rows x 128 cols; wave = 64x64 (wr=wave>>1, wc=wave&1).
// Grid (ceil(M/256), 2) = 392 blocks <= 512 slots (2 blocks/CU at 64KB LDS) = 1 occupancy
// wave, 16 waves/CU. launch_bounds(512,4) caps VGPR at 128 (acc 64 + am 16 + bn 16).
// B chunks XOR-swizzled via pre-swizzled gld_lds16 source (read-side <=2-way conflicts).
// Epilogue Cs aliases B (dead after main loop; barriers guard reuse).
template <int STATS>
__global__ __launch_bounds__(512, 4) void gemm_big(const u16* __restrict__ A, const u16* __restrict__ BT,
                                                   const float* __restrict__ bias, u16* __restrict__ C,
                                                   float* __restrict__ sums, int M) {
    __shared__ u16 ldsB[32768];   // 64 KB: 128 BT-rows x 256 u16, 16B-chunk swizzled
    int tid = threadIdx.x;
    int wave = tid >> 6, lane = tid & 63, l15 = lane & 15, quad = lane >> 4;
    int row0 = blockIdx.x * 256;
    int col0 = blockIdx.y * 128;
    int wr = (wave >> 1) * 64, wc = (wave & 1) * 64;

    // stage B once: 4096 chunks of 16B; chunk slot cl of row n holds source chunk cl^(n&7)
#pragma unroll
    for (int i = 0; i < 8; i++) {
        int g = wave * 8 + i;                 // 64-chunk group 0..63
        int c = g * 64 + lane;                // chunk 0..4095
        int n = c >> 5, cl = c & 31;
        int cs = cl ^ (n & 7);
        gld_lds16(BT + (long)(col0 + n) * 256 + cs * 8, ldsB + g * 512);
    }

    floatx4 acc[4][4];
    floatx4 zero = {0.f, 0.f, 0.f, 0.f};
#pragma unroll
    for (int mi = 0; mi < 4; mi++)
#pragma unroll
        for (int ni = 0; ni < 4; ni++) acc[mi][ni] = zero;

    // hoist per-wave A row bases (tail rows clamped; stores are guarded)
    const u16* arow[4];
#pragma unroll
    for (int i = 0; i < 4; i++)
        arow[i] = A + (long)min(row0 + wr + i * 16 + l15, M - 1) * 256 + quad * 8;

    __syncthreads();   // B resident (includes vmcnt drain)

    // barrier-free main loop: 8 k-steps x (4 A-loads + 4 B ds_reads + 16 MFMA)
#pragma unroll
    for (int kk = 0; kk < 8; kk++) {
        short8 am[4], bn[4];
#pragma unroll
        for (int i = 0; i < 4; i++) {
            am[i] = *(const short8*)(arow[i] + kk * 32);
            int nb = wc + i * 16 + l15;
            bn[i] = *(const short8*)(ldsB + nb * 256 + (((kk * 4 + quad) ^ (nb & 7)) * 8));
        }
#pragma unroll
        for (int mi = 0; mi < 4; mi++)
#pragma unroll
            for (int ni = 0; ni < 4; ni++)
                acc[mi][ni] = __builtin_amdgcn_mfma_f32_16x16x32_bf16(am[mi], bn[ni], acc[mi][ni], 0, 0, 0);
    }

    // ---- epilogue: bias (+ BN column stats), then coalesced store via Cs transpose ----
    u16* Cs = ldsB;   // 64x136 u16 = 8704, aliases B (dead; barriers below guard reuse)
    float s[4], s2[4];
    if (STATS) {
#pragma unroll
        for (int ni = 0; ni < 4; ni++) { s[ni] = 0.f; s2[ni] = 0.f; }
    }
#pragma unroll
    for (int ni = 0; ni < 4; ni++) {
        int gcol = col0 + wc + ni * 16 + l15;
        float bv = bias[gcol];
#pragma unroll
        for (int mi = 0; mi < 4; mi++)
#pragma unroll
            for (int r = 0; r < 4; r++) {
                float v = acc[mi][ni][r] + bv;
                acc[mi][ni][r] = v;
                if (STATS) {
                    int grow = row0 + wr + mi * 16 + quad * 4 + r;
                    if (grow < M) { s[ni] += v; s2[ni] = fmaf(v, v, s2[ni]); }
                }
            }
    }
    if (STATS) {
#pragma unroll
        for (int ni = 0; ni < 4; ni++) {
            float a = s[ni], b = s2[ni];
            a += __shfl_xor(a, 16, 64); a += __shfl_xor(a, 32, 64);
            b += __shfl_xor(b, 16, 64); b += __shfl_xor(b, 32, 64);
            if (quad == 0) {
                int gcol = col0 + wc + ni * 16 + l15;
                unsafeAtomicAdd(&sums[gcol], a);
                unsafeAtomicAdd(&sums[256 + gcol], b);
            }
        }
    }
    // four 64-row groups: waves with (wave>>1)==h write their 64x64 into Cs; all copy out
#pragma unroll
    for (int h = 0; h < 4; h++) {
        __syncthreads();
        if ((wave >> 1) == h) {
#pragma unroll
            for (int mi = 0; mi < 4; mi++)
#pragma unroll
                for (int ni = 0; ni < 4; ni++)
#pragma unroll
                    for (int r = 0; r < 4; r++)
                        Cs[(mi * 16 + quad * 4 + r) * 136 + wc + ni * 16 + l15] = f2b(acc[mi][ni][r]);
        }
        __syncthreads();
        {   // thread t: row t>>3, 32B chunk t&7 (64 rows x 128 cols)
            int r = tid >> 3, ch = tid & 7;
            int grow = row0 + h * 64 + r;
            if (grow < M) {
                const u16* src = Cs + r * 136 + ch * 16;
                u16* dst = C + (long)grow * 256 + col0 + ch * 16;
                uint4 v0 = *(const uint4*)(src);
                uint4 v1 = *(const uint4*)(src + 8);
                *(uint4*)(dst) = v0;
                *(uint4*)(dst + 8) = v1;
            }
        }
    }
}

// ---------- BN coefficients: scale/shift per column ----------
__global__ __launch_bounds__(256) void bn_coef(const float* __restrict__ sums, const float* __restrict__ gamma,
                                               const float* __restrict__ beta, float* __restrict__ coef, int N) {
    int c = threadIdx.x;
    float invN = 1.0f / (float)N;
    float mean = sums[c] * invN;
    float var = sums[256 + c] * invN - mean * mean;
    float s = gamma[c] * rsqrtf(var + 1e-5f);
    coef[c] = s;
    coef[256 + c] = beta[c] - mean * s;
}

// ---------- predictor v7-split: same per-wave structure; qoff = block offset ----------
__global__ __launch_bounds__(512, 2) void predictor(const u16* __restrict__ h2b, const int* __restrict__ e0,
                                                    const int* __restrict__ e1, const u16* __restrict__ pW1T,
                                                    const float* __restrict__ pb1, const float* __restrict__ pW2,
                                                    const float* __restrict__ pb2, float* __restrict__ out,
                                                    int Q, int qoff) {
    __shared__ u16 Bs[2][32 * 256];   // 2 x 16 KB double buffer
    int tid = threadIdx.x;
    int wave = tid >> 6, lane = tid & 63, l15 = lane & 15, quad = lane >> 4;

    // async stage of 32 weight rows (phase p) into buf; XOR swizzle folded into source address
    auto stage = [&](int p, u16* buf) {
#pragma unroll
        for (int i = 0; i < 2; i++) {
            int m = wave * 2 + i;                 // 1 KB chunk, 16 chunks = 16 KB
            int nl = m * 2 + (lane >> 5);         // local n row 0..31
            int cl = lane & 31;                   // swizzled 16B slot
            int cs = cl ^ (nl & 7);               // source chunk
            const u16* g = pW1T + (long)(p * 32 + nl) * 256 + cs * 8;
            gld_lds16(g, buf + m * 512);          // lane writes at +lane*16B
        }
    };

    stage(0, Bs[0]);   // in flight under the z-gathers

    int q0 = (qoff + blockIdx.x) * 256;
    short8 za[2][8];
#pragma unroll
    for (int mt = 0; mt < 2; mt++) {
        int q = min(q0 + wave * 32 + mt * 16 + l15, Q - 1);
        long u = (long)e0[q] * 256, v = (long)e1[q] * 256;
#pragma unroll
        for (int ki = 0; ki < 8; ki++) {
            uint4 a = *(const uint4*)(h2b + u + ki * 32 + quad * 8);
            uint4 b = *(const uint4*)(h2b + v + ki * 32 + quad * 8);
            uint4 z;
            z.x = pkmul(a.x, b.x);
            z.y = pkmul(a.y, b.y);
            z.z = pkmul(a.z, b.z);
            z.w = pkmul(a.w, b.w);
            za[mt][ki] = *(short8*)&z;
        }
    }
    float rs[2][4] = {{0.f, 0.f, 0.f, 0.f}, {0.f, 0.f, 0.f, 0.f}};
    floatx4 zero = {0.f, 0.f, 0.f, 0.f};

#pragma unroll
    for (int p = 0; p < 8; p++) {
        if (p < 7) {
            stage(p + 1, Bs[(p + 1) & 1]);
            asm volatile("s_waitcnt vmcnt(2)" ::: "memory");
        } else {
            asm volatile("s_waitcnt vmcnt(0)" ::: "memory");
        }
        __builtin_amdgcn_s_barrier();             // buf[p&1] globally ready
        const u16* buf = Bs[p & 1];
        float bb[2], w2[2];
#pragma unroll
        for (int nt = 0; nt < 2; nt++) {
            int col = p * 32 + nt * 16 + l15;
            bb[nt] = pb1[col];
            w2[nt] = pW2[col];
        }
        floatx4 acc[2][2];
#pragma unroll
        for (int mt = 0; mt < 2; mt++) { acc[mt][0] = zero; acc[mt][1] = zero; }
        __builtin_amdgcn_s_setprio(1);
#pragma unroll
        for (int ki = 0; ki < 8; ki++) {
#pragma unroll
            for (int nt = 0; nt < 2; nt++) {
                int nl = nt * 16 + l15;
                int cs = (ki * 4 + quad) ^ (nl & 7);
                short8 b = *(const short8*)(buf + nl * 256 + cs * 8);
#pragma unroll
                for (int mt = 0; mt < 2; mt++)
                    acc[mt][nt] = __builtin_amdgcn_mfma_f32_16x16x32_bf16(za[mt][ki], b, acc[mt][nt], 0, 0, 0);
            }
        }
        __builtin_amdgcn_s_setprio(0);
        if (p < 7) __builtin_amdgcn_s_barrier();  // all waves done reading buf[p&1]
        // fold this phase's 32 cols into rs (register-only, overlaps next stage's flight)
#pragma unroll
        for (int nt = 0; nt < 2; nt++)
#pragma unroll
            for (int mt = 0; mt < 2; mt++)
#pragma unroll
                for (int r = 0; r < 4; r++)
                    rs[mt][r] = fmaf(fmaxf(acc[mt][nt][r] + bb[nt], 0.f), w2[nt], rs[mt][r]);
    }
    // reduce across the 16 col-lanes
#pragma unroll
    for (int m = 1; m < 16; m <<= 1)
#pragma unroll
        for (int mt = 0; mt < 2; mt++)
#pragma unroll
            for (int r = 0; r < 4; r++)
                rs[mt][r] += __shfl_xor(rs[mt][r], m, 64);
    if (l15 == 0) {
        float b2v = pb2[0];
#pragma unroll
        for (int mt = 0; mt < 2; mt++)
#pragma unroll
            for (int r = 0; r < 4; r++) {
                int qq = q0 + wave * 32 + mt * 16 + quad * 4 + r;
                if (qq < Q) out[qq] = 1.0f / (1.0f + __expf(-(rs[mt][r] + b2v)));
            }
    }
}

extern "C" void kernel_launch(void* const* d_in, const int* in_sizes, int n_in,
                              void* d_out, int out_size, void* d_ws, size_t ws_size,
                              hipStream_t stream) {
    const float* x      = (const float*)d_in[0];
    const int*   adj_row= (const int*)d_in[1];
    const int*   adj_col= (const int*)d_in[2];
    const int*   edges  = (const int*)d_in[3];
    const float* emb    = (const float*)d_in[4];
    const float* W1     = (const float*)d_in[5];
    const float* b1     = (const float*)d_in[6];
    const float* W2     = (const float*)d_in[7];
    const float* b2     = (const float*)d_in[8];
    const float* gamma  = (const float*)d_in[9];
    const float* beta   = (const float*)d_in[10];
    const float* pW1    = (const float*)d_in[11];
    const float* pb1    = (const float*)d_in[12];
    const float* pW2    = (const float*)d_in[13];
    const float* pb2    = (const float*)d_in[14];
    float* out = (float*)d_out;

    int N = in_sizes[0] / 128;
    int E = in_sizes[1];
    int Q = in_sizes[3] / 2;

    char* ws = (char*)d_ws;
    size_t off = 0;
    auto alloc = [&](size_t bytes) -> char* {
        char* p = ws + off;
        off += (bytes + 255) & ~(size_t)255;
        return p;
    };
    // --- contiguous zero-init region: deg_cnt | cursor | sums | gcur (ONE memset) ---
    size_t npad = ((size_t)N * 4 + 255) & ~(size_t)255;
    int*   deg_cnt = (int*)alloc((size_t)N * 4);
    int*   cursor  = (int*)alloc((size_t)N * 4);
    float* sums    = (float*)alloc(512 * 4);
    int*   gcur    = (int*)alloc(4);
    size_t zspan   = npad * 2 + 2048 + 256;
    // --- rest ---
    int*   offs    = (int*)alloc((size_t)N * 4);
    float* dinv    = (float*)alloc((size_t)N * 4);
    int*   scol    = (int*)alloc((size_t)E * 4);
    float* coef    = (float*)alloc(512 * 4);
    u16*   WT      = (u16*)alloc((size_t)3 * 65536 * 2);
    u16*   bufA    = (u16*)alloc((size_t)N * 256 * 2);
    u16*   bufB    = (u16*)alloc((size_t)N * 256 * 2);
    u16*   bufC    = (u16*)alloc((size_t)N * 256 * 2);

    hipMemsetAsync(deg_cnt, 0, zspan, stream);

    int eb  = (E + 255) / 256;
    int NB  = (N + 255) / 256;
    int nb4 = (N * 64 + 255) / 256;
    int ab  = (N + 7) / 8;
    dim3 gemmGrid((N + 255) / 256, 2);

    count_deg<<<eb, 256, 0, stream>>>(adj_row, deg_cnt, E);
    alloc_offs<<<NB, 256, 0, stream>>>(deg_cnt, offs, dinv, gcur, N);
    sort_edges<<<eb, 256, 0, stream>>>(adj_row, adj_col, offs, cursor, scol, E);
    prep_wh<<<768 + nb4, 256, 0, stream>>>(W1, W2, pW1, WT, emb, x, bufA, N);

    // conv1 (commuted): h1 = agg(h0) @ W1 + b1, with fused BN column stats
    aggregate2<0><<<ab, 256, 0, stream>>>(bufA, offs, deg_cnt, scol, dinv, nullptr, bufB, N);
    gemm_big<1><<<gemmGrid, 512, 0, stream>>>(bufB, WT, b1, bufC, sums, N);
    bn_coef<<<1, 256, 0, stream>>>(sums, gamma, beta, coef, N);
    // conv2 (commuted): h2 = agg(relu(bn(h1))) @ W2 + b2, BN+ReLU fused into gather
    aggregate2<1><<<ab, 256, 0, stream>>>(bufC, offs, deg_cnt, scol, dinv, coef, bufB, N);
    gemm_big<0><<<gemmGrid, 512, 0, stream>>>(bufB, WT + 65536, b2, bufC, nullptr, N);
    // link predictor: two half-grid launches (diagnostic split; see round-7 note)
    int PB = (Q + 255) / 256;
    int PB1 = PB / 2;
    predictor<<<PB1, 512, 0, stream>>>(bufC, edges, edges + Q,
                                       WT + 131072, pb1, pW2, pb2, out, Q, 0);
    predictor<<<PB - PB1, 512, 0, stream>>>(bufC, edges, edges + Q,
                                            WT + 131072, pb1, pW2, pb2, out, Q, PB1);
}

// Round 11
// 389.225 us; speedup vs baseline: 1.0205x; 1.0096x over previous
//
#include <hip/hip_runtime.h>

typedef unsigned short u16;
typedef unsigned int u32;
typedef __attribute__((ext_vector_type(8))) short short8;
typedef __attribute__((ext_vector_type(4))) float floatx4;

// ---------- bf16 helpers ----------
__device__ __forceinline__ float b2f(u32 bits) { union { u32 u; float f; } c; c.u = bits << 16; return c.f; }
__device__ __forceinline__ float b2f_lo(u32 w) { union { u32 u; float f; } c; c.u = w << 16; return c.f; }
__device__ __forceinline__ float b2f_hi(u32 w) { union { u32 u; float f; } c; c.u = w & 0xFFFF0000u; return c.f; }
__device__ __forceinline__ u16 f2b(float f) {
    union { float f; u32 u; } c; c.f = f;
    u32 u = c.u;
    return (u16)((u + 0x7FFFu + ((u >> 16) & 1u)) >> 16);   // RNE
}
// packed bf16 mul, round-half-up (bias ~2^-16 rel)
__device__ __forceinline__ u32 pkmul(u32 a, u32 b) {
    union { u32 u; float f; } alo, ahi, blo, bhi, rlo, rhi;
    alo.u = a << 16; ahi.u = a & 0xFFFF0000u;
    blo.u = b << 16; bhi.u = b & 0xFFFF0000u;
    rlo.f = alo.f * blo.f; rhi.f = ahi.f * bhi.f;
    u32 lo = rlo.u + 0x8000u, hi = rhi.u + 0x8000u;
    return __builtin_amdgcn_perm(hi, lo, 0x07060302u);
}
// async global->LDS, 16B per lane; lds base must be wave-uniform
__device__ __forceinline__ void gld_lds16(const u16* g, u16* l) {
    __builtin_amdgcn_global_load_lds((const __attribute__((address_space(1))) u32*)g,
                                     (__attribute__((address_space(3))) u32*)l, 16, 0, 0);
}

// ---------- graph prep ----------
__global__ __launch_bounds__(256) void count_deg(const int* __restrict__ row, int* __restrict__ cnt, int E) {
    int e = blockIdx.x * 256 + threadIdx.x;
    if (e < E) atomicAdd(&cnt[row[e]], 1);
}

// CSR segment allocation WITHOUT ordered scan: wave-prefix + 1 atomic bump per wave.
__global__ __launch_bounds__(256) void alloc_offs(const int* __restrict__ cnt, int* __restrict__ offs,
                                                  float* __restrict__ dinv, int* __restrict__ gcur, int N) {
    int i = blockIdx.x * 256 + threadIdx.x;
    int lane = threadIdx.x & 63;
    int c = (i < N) ? cnt[i] : 0;
    int sc = c;
#pragma unroll
    for (int o = 1; o < 64; o <<= 1) {
        int u = __shfl_up(sc, o, 64);
        if (lane >= o) sc += u;
    }
    int ex = sc - c;                       // exclusive prefix within wave
    int total = __shfl(sc, 63, 64);        // wave total
    int base = 0;
    if (lane == 63) base = atomicAdd(gcur, total);
    base = __shfl(base, 63, 64);
    if (i < N) {
        offs[i] = base + ex;
        dinv[i] = rsqrtf((float)c + 1.0f);
    }
}

__global__ __launch_bounds__(256) void sort_edges(const int* __restrict__ row, const int* __restrict__ col,
                                                  const int* __restrict__ offs, int* __restrict__ cursor,
                                                  int* __restrict__ scol, int E) {
    int e = blockIdx.x * 256 + threadIdx.x;
    if (e < E) {
        int r = row[e];
        int p = offs[r] + atomicAdd(&cursor[r], 1);
        scol[p] = col[e];
    }
}

// ---------- fused weight prep + h0 concat (one launch) ----------
__global__ __launch_bounds__(256) void prep_wh(const float* __restrict__ W1, const float* __restrict__ W2,
                                               const float* __restrict__ pW1, u16* __restrict__ WT,
                                               const float* __restrict__ emb, const float* __restrict__ x,
                                               u16* __restrict__ h0b, int N) {
    int b = blockIdx.x;
    if (b < 768) {
        int tid = b * 256 + threadIdx.x;
        int which = tid >> 16, id = tid & 65535;
        int n = id >> 8, k = id & 255;
        const float* W = (which == 0) ? W1 : ((which == 1) ? W2 : pW1);
        WT[tid] = f2b(W[k * 256 + n]);
    } else {
        int t = (b - 768) * 256 + threadIdx.x;
        long base = (long)t * 4;
        if (base >= (long)N * 256) return;
        int i = (int)(base >> 8), k = (int)(base & 255);
        const float* src = (k < 128) ? (emb + (long)i * 128 + k) : (x + (long)i * 128 + (k - 128));
        float4 v = *(const float4*)src;
        ushort4 o;
        o.x = f2b(v.x); o.y = f2b(v.y); o.z = f2b(v.z); o.w = f2b(v.w);
        *(ushort4*)(h0b + base) = o;
    }
}

// ---------- aggregation: 1 node per half-wave (32 lanes x uint4 = full 512B row) ----------
template <int FUSED_BN>
__global__ __launch_bounds__(256) void aggregate2(const u16* __restrict__ h, const int* __restrict__ offs,
                                                  const int* __restrict__ cnt, const int* __restrict__ scol,
                                                  const float* __restrict__ dinv, const float* __restrict__ coef,
                                                  u16* __restrict__ out, int N) {
    int hw = threadIdx.x >> 5, lane = threadIdx.x & 31;
    int node = blockIdx.x * 8 + hw;
    if (node >= N) return;
    float sc[8], sh[8];
    if (FUSED_BN) {
#pragma unroll
        for (int i = 0; i < 8; i++) { sc[i] = coef[lane * 8 + i]; sh[i] = coef[256 + lane * 8 + i]; }
    }
    float a[8];
#pragma unroll
    for (int i = 0; i < 8; i++) a[i] = 0.f;

    auto rowAcc = [&](uint4 u, float d) {
        float f[8];
        f[0] = b2f_lo(u.x); f[1] = b2f_hi(u.x);
        f[2] = b2f_lo(u.y); f[3] = b2f_hi(u.y);
        f[4] = b2f_lo(u.z); f[5] = b2f_hi(u.z);
        f[6] = b2f_lo(u.w); f[7] = b2f_hi(u.w);
#pragma unroll
        for (int i = 0; i < 8; i++) {
            float v = f[i];
            if (FUSED_BN) v = fmaxf(fmaf(v, sc[i], sh[i]), 0.f);
            a[i] = fmaf(v, d, a[i]);
        }
    };
    int beg = offs[node], end = beg + cnt[node];
    int j = beg;
    for (; j + 3 < end; j += 4) {
        int c0 = scol[j], c1 = scol[j + 1], c2 = scol[j + 2], c3 = scol[j + 3];
        float d0 = dinv[c0], d1 = dinv[c1], d2 = dinv[c2], d3 = dinv[c3];
        uint4 v0 = *(const uint4*)(h + (long)c0 * 256 + lane * 8);
        uint4 v1 = *(const uint4*)(h + (long)c1 * 256 + lane * 8);
        uint4 v2 = *(const uint4*)(h + (long)c2 * 256 + lane * 8);
        uint4 v3 = *(const uint4*)(h + (long)c3 * 256 + lane * 8);
        rowAcc(v0, d0); rowAcc(v1, d1); rowAcc(v2, d2); rowAcc(v3, d3);
    }
    for (; j < end; j++) {
        int c0 = scol[j];
        float d0 = dinv[c0];
        uint4 v0 = *(const uint4*)(h + (long)c0 * 256 + lane * 8);
        rowAcc(v0, d0);
    }
    float di = dinv[node];
    {
        uint4 u = *(const uint4*)(h + (long)node * 256 + lane * 8);
        rowAcc(u, di);   // self term with weight di (total = sum + di*self)
    }
    u16 ob[8];
#pragma unroll
    for (int i = 0; i < 8; i++) ob[i] = f2b(di * a[i]);
    ushort4 o0, o1;
    o0.x = ob[0]; o0.y = ob[1]; o0.z = ob[2]; o0.w = ob[3];
    o1.x = ob[4]; o1.y = ob[5]; o1.z = ob[6]; o1.w = ob[7];
    *(ushort4*)(out + (long)node * 256 + lane * 8) = o0;
    *(ushort4*)(out + (long)node * 256 + lane * 8 + 4) = o1;
}

// ---------- GEMM v6: B-resident LDS (64KB), barrier-free A-streaming main loop ----------
// (R10: -4.3us wall-clock vs v4. Profiled durations are replay-inflated — A is L2-hot in
// the real pipeline, cold under rocprof replay. Wall clock is ground truth.)
template <int STATS>
__global__ __launch_bounds__(512, 4) void gemm_big(const u16* __restrict__ A, const u16* __restrict__ BT,
                                                   const float* __restrict__ bias, u16* __restrict__ C,
                                                   float* __restrict__ sums, int M) {
    __shared__ u16 ldsB[32768];   // 64 KB: 128 BT-rows x 256 u16, 16B-chunk swizzled
    int tid = threadIdx.x;
    int wave = tid >> 6, lane = tid & 63, l15 = lane & 15, quad = lane >> 4;
    int row0 = blockIdx.x * 256;
    int col0 = blockIdx.y * 128;
    int wr = (wave >> 1) * 64, wc = (wave & 1) * 64;

    // stage B once: 4096 chunks of 16B; chunk slot cl of row n holds source chunk cl^(n&7)
#pragma unroll
    for (int i = 0; i < 8; i++) {
        int g = wave * 8 + i;                 // 64-chunk group 0..63
        int c = g * 64 + lane;                // chunk 0..4095
        int n = c >> 5, cl = c & 31;
        int cs = cl ^ (n & 7);
        gld_lds16(BT + (long)(col0 + n) * 256 + cs * 8, ldsB + g * 512);
    }

    floatx4 acc[4][4];
    floatx4 zero = {0.f, 0.f, 0.f, 0.f};
#pragma unroll
    for (int mi = 0; mi < 4; mi++)
#pragma unroll
        for (int ni = 0; ni < 4; ni++) acc[mi][ni] = zero;

    // hoist per-wave A row bases (tail rows clamped; stores are guarded)
    const u16* arow[4];
#pragma unroll
    for (int i = 0; i < 4; i++)
        arow[i] = A + (long)min(row0 + wr + i * 16 + l15, M - 1) * 256 + quad * 8;

    __syncthreads();   // B resident (includes vmcnt drain)

    // barrier-free main loop: 8 k-steps x (4 A-loads + 4 B ds_reads + 16 MFMA)
#pragma unroll
    for (int kk = 0; kk < 8; kk++) {
        short8 am[4], bn[4];
#pragma unroll
        for (int i = 0; i < 4; i++) {
            am[i] = *(const short8*)(arow[i] + kk * 32);
            int nb = wc + i * 16 + l15;
            bn[i] = *(const short8*)(ldsB + nb * 256 + (((kk * 4 + quad) ^ (nb & 7)) * 8));
        }
#pragma unroll
        for (int mi = 0; mi < 4; mi++)
#pragma unroll
            for (int ni = 0; ni < 4; ni++)
                acc[mi][ni] = __builtin_amdgcn_mfma_f32_16x16x32_bf16(am[mi], bn[ni], acc[mi][ni], 0, 0, 0);
    }

    // ---- epilogue: bias (+ BN column stats), then coalesced store via Cs transpose ----
    u16* Cs = ldsB;   // 64x136 u16 = 8704, aliases B (dead; barriers below guard reuse)
    float s[4], s2[4];
    if (STATS) {
#pragma unroll
        for (int ni = 0; ni < 4; ni++) { s[ni] = 0.f; s2[ni] = 0.f; }
    }
#pragma unroll
    for (int ni = 0; ni < 4; ni++) {
        int gcol = col0 + wc + ni * 16 + l15;
        float bv = bias[gcol];
#pragma unroll
        for (int mi = 0; mi < 4; mi++)
#pragma unroll
            for (int r = 0; r < 4; r++) {
                float v = acc[mi][ni][r] + bv;
                acc[mi][ni][r] = v;
                if (STATS) {
                    int grow = row0 + wr + mi * 16 + quad * 4 + r;
                    if (grow < M) { s[ni] += v; s2[ni] = fmaf(v, v, s2[ni]); }
                }
            }
    }
    if (STATS) {
#pragma unroll
        for (int ni = 0; ni < 4; ni++) {
            float a = s[ni], b = s2[ni];
            a += __shfl_xor(a, 16, 64); a += __shfl_xor(a, 32, 64);
            b += __shfl_xor(b, 16, 64); b += __shfl_xor(b, 32, 64);
            if (quad == 0) {
                int gcol = col0 + wc + ni * 16 + l15;
                unsafeAtomicAdd(&sums[gcol], a);
                unsafeAtomicAdd(&sums[256 + gcol], b);
            }
        }
    }
    // four 64-row groups: waves with (wave>>1)==h write their 64x64 into Cs; all copy out
#pragma unroll
    for (int h = 0; h < 4; h++) {
        __syncthreads();
        if ((wave >> 1) == h) {
#pragma unroll
            for (int mi = 0; mi < 4; mi++)
#pragma unroll
                for (int ni = 0; ni < 4; ni++)
#pragma unroll
                    for (int r = 0; r < 4; r++)
                        Cs[(mi * 16 + quad * 4 + r) * 136 + wc + ni * 16 + l15] = f2b(acc[mi][ni][r]);
        }
        __syncthreads();
        {   // thread t: row t>>3, 32B chunk t&7 (64 rows x 128 cols)
            int r = tid >> 3, ch = tid & 7;
            int grow = row0 + h * 64 + r;
            if (grow < M) {
                const u16* src = Cs + r * 136 + ch * 16;
                u16* dst = C + (long)grow * 256 + col0 + ch * 16;
                uint4 v0 = *(const uint4*)(src);
                uint4 v1 = *(const uint4*)(src + 8);
                *(uint4*)(dst) = v0;
                *(uint4*)(dst + 8) = v1;
            }
        }
    }
}

// ---------- BN coefficients: scale/shift per column ----------
__global__ __launch_bounds__(256) void bn_coef(const float* __restrict__ sums, const float* __restrict__ gamma,
                                               const float* __restrict__ beta, float* __restrict__ coef, int N) {
    int c = threadIdx.x;
    float invN = 1.0f / (float)N;
    float mean = sums[c] * invN;
    float var = sums[256 + c] * invN - mean * mean;
    float s = gamma[c] * rsqrtf(var + 1e-5f);
    coef[c] = s;
    coef[256 + c] = beta[c] - mean * s;
}

// ---------- predictor v7: 8 waves x 32 queries = 256 q/block, single launch ----------
__global__ __launch_bounds__(512, 2) void predictor(const u16* __restrict__ h2b, const int* __restrict__ e0,
                                                    const int* __restrict__ e1, const u16* __restrict__ pW1T,
                                                    const float* __restrict__ pb1, const float* __restrict__ pW2,
                                                    const float* __restrict__ pb2, float* __restrict__ out, int Q) {
    __shared__ u16 Bs[2][32 * 256];   // 2 x 16 KB double buffer
    int tid = threadIdx.x;
    int wave = tid >> 6, lane = tid & 63, l15 = lane & 15, quad = lane >> 4;

    // async stage of 32 weight rows (phase p) into buf; XOR swizzle folded into source address
    auto stage = [&](int p, u16* buf) {
#pragma unroll
        for (int i = 0; i < 2; i++) {
            int m = wave * 2 + i;                 // 1 KB chunk, 16 chunks = 16 KB
            int nl = m * 2 + (lane >> 5);         // local n row 0..31
            int cl = lane & 31;                   // swizzled 16B slot
            int cs = cl ^ (nl & 7);               // source chunk
            const u16* g = pW1T + (long)(p * 32 + nl) * 256 + cs * 8;
            gld_lds16(g, buf + m * 512);          // lane writes at +lane*16B
        }
    };

    stage(0, Bs[0]);   // in flight under the z-gathers

    int q0 = blockIdx.x * 256;
    short8 za[2][8];
#pragma unroll
    for (int mt = 0; mt < 2; mt++) {
        int q = min(q0 + wave * 32 + mt * 16 + l15, Q - 1);
        long u = (long)e0[q] * 256, v = (long)e1[q] * 256;
#pragma unroll
        for (int ki = 0; ki < 8; ki++) {
            uint4 a = *(const uint4*)(h2b + u + ki * 32 + quad * 8);
            uint4 b = *(const uint4*)(h2b + v + ki * 32 + quad * 8);
            uint4 z;
            z.x = pkmul(a.x, b.x);
            z.y = pkmul(a.y, b.y);
            z.z = pkmul(a.z, b.z);
            z.w = pkmul(a.w, b.w);
            za[mt][ki] = *(short8*)&z;
        }
    }
    float rs[2][4] = {{0.f, 0.f, 0.f, 0.f}, {0.f, 0.f, 0.f, 0.f}};
    floatx4 zero = {0.f, 0.f, 0.f, 0.f};

#pragma unroll
    for (int p = 0; p < 8; p++) {
        if (p < 7) {
            stage(p + 1, Bs[(p + 1) & 1]);
            asm volatile("s_waitcnt vmcnt(2)" ::: "memory");
        } else {
            asm volatile("s_waitcnt vmcnt(0)" ::: "memory");
        }
        __builtin_amdgcn_s_barrier();             // buf[p&1] globally ready
        const u16* buf = Bs[p & 1];
        float bb[2], w2[2];
#pragma unroll
        for (int nt = 0; nt < 2; nt++) {
            int col = p * 32 + nt * 16 + l15;
            bb[nt] = pb1[col];
            w2[nt] = pW2[col];
        }
        floatx4 acc[2][2];
#pragma unroll
        for (int mt = 0; mt < 2; mt++) { acc[mt][0] = zero; acc[mt][1] = zero; }
        __builtin_amdgcn_s_setprio(1);
#pragma unroll
        for (int ki = 0; ki < 8; ki++) {
#pragma unroll
            for (int nt = 0; nt < 2; nt++) {
                int nl = nt * 16 + l15;
                int cs = (ki * 4 + quad) ^ (nl & 7);
                short8 b = *(const short8*)(buf + nl * 256 + cs * 8);
#pragma unroll
                for (int mt = 0; mt < 2; mt++)
                    acc[mt][nt] = __builtin_amdgcn_mfma_f32_16x16x32_bf16(za[mt][ki], b, acc[mt][nt], 0, 0, 0);
            }
        }
        __builtin_amdgcn_s_setprio(0);
        if (p < 7) __builtin_amdgcn_s_barrier();  // all waves done reading buf[p&1]
        // fold this phase's 32 cols into rs (register-only, overlaps next stage's flight)
#pragma unroll
        for (int nt = 0; nt < 2; nt++)
#pragma unroll
            for (int mt = 0; mt < 2; mt++)
#pragma unroll
                for (int r = 0; r < 4; r++)
                    rs[mt][r] = fmaf(fmaxf(acc[mt][nt][r] + bb[nt], 0.f), w2[nt], rs[mt][r]);
    }
    // reduce across the 16 col-lanes
#pragma unroll
    for (int m = 1; m < 16; m <<= 1)
#pragma unroll
        for (int mt = 0; mt < 2; mt++)
#pragma unroll
            for (int r = 0; r < 4; r++)
                rs[mt][r] += __shfl_xor(rs[mt][r], m, 64);
    if (l15 == 0) {
        float b2v = pb2[0];
#pragma unroll
        for (int mt = 0; mt < 2; mt++)
#pragma unroll
            for (int r = 0; r < 4; r++) {
                int qq = q0 + wave * 32 + mt * 16 + quad * 4 + r;
                if (qq < Q) out[qq] = 1.0f / (1.0f + __expf(-(rs[mt][r] + b2v)));
            }
    }
}

extern "C" void kernel_launch(void* const* d_in, const int* in_sizes, int n_in,
                              void* d_out, int out_size, void* d_ws, size_t ws_size,
                              hipStream_t stream) {
    const float* x      = (const float*)d_in[0];
    const int*   adj_row= (const int*)d_in[1];
    const int*   adj_col= (const int*)d_in[2];
    const int*   edges  = (const int*)d_in[3];
    const float* emb    = (const float*)d_in[4];
    const float* W1     = (const float*)d_in[5];
    const float* b1     = (const float*)d_in[6];
    const float* W2     = (const float*)d_in[7];
    const float* b2     = (const float*)d_in[8];
    const float* gamma  = (const float*)d_in[9];
    const float* beta   = (const float*)d_in[10];
    const float* pW1    = (const float*)d_in[11];
    const float* pb1    = (const float*)d_in[12];
    const float* pW2    = (const float*)d_in[13];
    const float* pb2    = (const float*)d_in[14];
    float* out = (float*)d_out;

    int N = in_sizes[0] / 128;
    int E = in_sizes[1];
    int Q = in_sizes[3] / 2;

    char* ws = (char*)d_ws;
    size_t off = 0;
    auto alloc = [&](size_t bytes) -> char* {
        char* p = ws + off;
        off += (bytes + 255) & ~(size_t)255;
        return p;
    };
    // --- contiguous zero-init region: deg_cnt | cursor | sums | gcur (ONE memset) ---
    size_t npad = ((size_t)N * 4 + 255) & ~(size_t)255;
    int*   deg_cnt = (int*)alloc((size_t)N * 4);
    int*   cursor  = (int*)alloc((size_t)N * 4);
    float* sums    = (float*)alloc(512 * 4);
    int*   gcur    = (int*)alloc(4);
    size_t zspan   = npad * 2 + 2048 + 256;
    // --- rest ---
    int*   offs    = (int*)alloc((size_t)N * 4);
    float* dinv    = (float*)alloc((size_t)N * 4);
    int*   scol    = (int*)alloc((size_t)E * 4);
    float* coef    = (float*)alloc(512 * 4);
    u16*   WT      = (u16*)alloc((size_t)3 * 65536 * 2);
    u16*   bufA    = (u16*)alloc((size_t)N * 256 * 2);
    u16*   bufB    = (u16*)alloc((size_t)N * 256 * 2);
    u16*   bufC    = (u16*)alloc((size_t)N * 256 * 2);

    hipMemsetAsync(deg_cnt, 0, zspan, stream);

    int eb  = (E + 255) / 256;
    int NB  = (N + 255) / 256;
    int nb4 = (N * 64 + 255) / 256;
    int ab  = (N + 7) / 8;
    dim3 gemmGrid((N + 255) / 256, 2);

    count_deg<<<eb, 256, 0, stream>>>(adj_row, deg_cnt, E);
    alloc_offs<<<NB, 256, 0, stream>>>(deg_cnt, offs, dinv, gcur, N);
    sort_edges<<<eb, 256, 0, stream>>>(adj_row, adj_col, offs, cursor, scol, E);
    prep_wh<<<768 + nb4, 256, 0, stream>>>(W1, W2, pW1, WT, emb, x, bufA, N);

    // conv1 (commuted): h1 = agg(h0) @ W1 + b1, with fused BN column stats
    aggregate2<0><<<ab, 256, 0, stream>>>(bufA, offs, deg_cnt, scol, dinv, nullptr, bufB, N);
    gemm_big<1><<<gemmGrid, 512, 0, stream>>>(bufB, WT, b1, bufC, sums, N);
    bn_coef<<<1, 256, 0, stream>>>(sums, gamma, beta, coef, N);
    // conv2 (commuted): h2 = agg(relu(bn(h1))) @ W2 + b2, BN+ReLU fused into gather
    aggregate2<1><<<ab, 256, 0, stream>>>(bufC, offs, deg_cnt, scol, dinv, coef, bufB, N);
    gemm_big<0><<<gemmGrid, 512, 0, stream>>>(bufB, WT + 65536, b2, bufC, nullptr, N);
    // link predictor (single launch; round-8 split measured +4.8us wall-clock)
    predictor<<<(Q + 255) / 256, 512, 0, stream>>>(bufC, edges, edges + Q,
                                                   WT + 131072, pb1, pW2, pb2, out, Q);
}

// Round 12
// 386.225 us; speedup vs baseline: 1.0284x; 1.0078x over previous
//
#include <hip/hip_runtime.h>

typedef unsigned short u16;
typedef unsigned int u32;
typedef __attribute__((ext_vector_type(8))) short short8;
typedef __attribute__((ext_vector_type(4))) float floatx4;

// ---------- bf16 helpers ----------
__device__ __forceinline__ float b2f(u32 bits) { union { u32 u; float f; } c; c.u = bits << 16; return c.f; }
__device__ __forceinline__ float b2f_lo(u32 w) { union { u32 u; float f; } c; c.u = w << 16; return c.f; }
__device__ __forceinline__ float b2f_hi(u32 w) { union { u32 u; float f; } c; c.u = w & 0xFFFF0000u; return c.f; }
__device__ __forceinline__ u16 f2b(float f) {
    union { float f; u32 u; } c; c.f = f;
    u32 u = c.u;
    return (u16)((u + 0x7FFFu + ((u >> 16) & 1u)) >> 16);   // RNE
}
// packed bf16 mul, round-half-up (bias ~2^-16 rel)
__device__ __forceinline__ u32 pkmul(u32 a, u32 b) {
    union { u32 u; float f; } alo, ahi, blo, bhi, rlo, rhi;
    alo.u = a << 16; ahi.u = a & 0xFFFF0000u;
    blo.u = b << 16; bhi.u = b & 0xFFFF0000u;
    rlo.f = alo.f * blo.f; rhi.f = ahi.f * bhi.f;
    u32 lo = rlo.u + 0x8000u, hi = rhi.u + 0x8000u;
    return __builtin_amdgcn_perm(hi, lo, 0x07060302u);
}
// async global->LDS, 16B per lane; lds base must be wave-uniform
__device__ __forceinline__ void gld_lds16(const u16* g, u16* l) {
    __builtin_amdgcn_global_load_lds((const __attribute__((address_space(1))) u32*)g,
                                     (__attribute__((address_space(3))) u32*)l, 16, 0, 0);
}

// ---------- graph prep ----------
__global__ __launch_bounds__(256) void count_deg(const int* __restrict__ row, int* __restrict__ cnt, int E) {
    int e = blockIdx.x * 256 + threadIdx.x;
    if (e < E) atomicAdd(&cnt[row[e]], 1);
}

// CSR segment allocation WITHOUT ordered scan: wave-prefix + 1 atomic bump per wave.
__global__ __launch_bounds__(256) void alloc_offs(const int* __restrict__ cnt, int* __restrict__ offs,
                                                  float* __restrict__ dinv, int* __restrict__ gcur, int N) {
    int i = blockIdx.x * 256 + threadIdx.x;
    int lane = threadIdx.x & 63;
    int c = (i < N) ? cnt[i] : 0;
    int sc = c;
#pragma unroll
    for (int o = 1; o < 64; o <<= 1) {
        int u = __shfl_up(sc, o, 64);
        if (lane >= o) sc += u;
    }
    int ex = sc - c;                       // exclusive prefix within wave
    int total = __shfl(sc, 63, 64);        // wave total
    int base = 0;
    if (lane == 63) base = atomicAdd(gcur, total);
    base = __shfl(base, 63, 64);
    if (i < N) {
        offs[i] = base + ex;
        dinv[i] = rsqrtf((float)c + 1.0f);
    }
}

__global__ __launch_bounds__(256) void sort_edges(const int* __restrict__ row, const int* __restrict__ col,
                                                  const int* __restrict__ offs, int* __restrict__ cursor,
                                                  int* __restrict__ scol, int E) {
    int e = blockIdx.x * 256 + threadIdx.x;
    if (e < E) {
        int r = row[e];
        int p = offs[r] + atomicAdd(&cursor[r], 1);
        scol[p] = col[e];
    }
}

// ---------- fused weight prep + h0 concat (one launch) ----------
__global__ __launch_bounds__(256) void prep_wh(const float* __restrict__ W1, const float* __restrict__ W2,
                                               const float* __restrict__ pW1, u16* __restrict__ WT,
                                               const float* __restrict__ emb, const float* __restrict__ x,
                                               u16* __restrict__ h0b, int N) {
    int b = blockIdx.x;
    if (b < 768) {
        int tid = b * 256 + threadIdx.x;
        int which = tid >> 16, id = tid & 65535;
        int n = id >> 8, k = id & 255;
        const float* W = (which == 0) ? W1 : ((which == 1) ? W2 : pW1);
        WT[tid] = f2b(W[k * 256 + n]);
    } else {
        int t = (b - 768) * 256 + threadIdx.x;
        long base = (long)t * 4;
        if (base >= (long)N * 256) return;
        int i = (int)(base >> 8), k = (int)(base & 255);
        const float* src = (k < 128) ? (emb + (long)i * 128 + k) : (x + (long)i * 128 + (k - 128));
        float4 v = *(const float4*)src;
        ushort4 o;
        o.x = f2b(v.x); o.y = f2b(v.y); o.z = f2b(v.z); o.w = f2b(v.w);
        *(ushort4*)(h0b + base) = o;
    }
}

// ---------- aggregation: 1 node per half-wave (32 lanes x uint4 = full 512B row) ----------
template <int FUSED_BN>
__global__ __launch_bounds__(256) void aggregate2(const u16* __restrict__ h, const int* __restrict__ offs,
                                                  const int* __restrict__ cnt, const int* __restrict__ scol,
                                                  const float* __restrict__ dinv, const float* __restrict__ coef,
                                                  u16* __restrict__ out, int N) {
    int hw = threadIdx.x >> 5, lane = threadIdx.x & 31;
    int node = blockIdx.x * 8 + hw;
    if (node >= N) return;
    float sc[8], sh[8];
    if (FUSED_BN) {
#pragma unroll
        for (int i = 0; i < 8; i++) { sc[i] = coef[lane * 8 + i]; sh[i] = coef[256 + lane * 8 + i]; }
    }
    float a[8];
#pragma unroll
    for (int i = 0; i < 8; i++) a[i] = 0.f;

    auto rowAcc = [&](uint4 u, float d) {
        float f[8];
        f[0] = b2f_lo(u.x); f[1] = b2f_hi(u.x);
        f[2] = b2f_lo(u.y); f[3] = b2f_hi(u.y);
        f[4] = b2f_lo(u.z); f[5] = b2f_hi(u.z);
        f[6] = b2f_lo(u.w); f[7] = b2f_hi(u.w);
#pragma unroll
        for (int i = 0; i < 8; i++) {
            float v = f[i];
            if (FUSED_BN) v = fmaxf(fmaf(v, sc[i], sh[i]), 0.f);
            a[i] = fmaf(v, d, a[i]);
        }
    };
    int beg = offs[node], end = beg + cnt[node];
    int j = beg;
    for (; j + 3 < end; j += 4) {
        int c0 = scol[j], c1 = scol[j + 1], c2 = scol[j + 2], c3 = scol[j + 3];
        float d0 = dinv[c0], d1 = dinv[c1], d2 = dinv[c2], d3 = dinv[c3];
        uint4 v0 = *(const uint4*)(h + (long)c0 * 256 + lane * 8);
        uint4 v1 = *(const uint4*)(h + (long)c1 * 256 + lane * 8);
        uint4 v2 = *(const uint4*)(h + (long)c2 * 256 + lane * 8);
        uint4 v3 = *(const uint4*)(h + (long)c3 * 256 + lane * 8);
        rowAcc(v0, d0); rowAcc(v1, d1); rowAcc(v2, d2); rowAcc(v3, d3);
    }
    for (; j < end; j++) {
        int c0 = scol[j];
        float d0 = dinv[c0];
        uint4 v0 = *(const uint4*)(h + (long)c0 * 256 + lane * 8);
        rowAcc(v0, d0);
    }
    float di = dinv[node];
    {
        uint4 u = *(const uint4*)(h + (long)node * 256 + lane * 8);
        rowAcc(u, di);   // self term with weight di (total = sum + di*self)
    }
    u16 ob[8];
#pragma unroll
    for (int i = 0; i < 8; i++) ob[i] = f2b(di * a[i]);
    ushort4 o0, o1;
    o0.x = ob[0]; o0.y = ob[1]; o0.z = ob[2]; o0.w = ob[3];
    o1.x = ob[4]; o1.y = ob[5]; o1.z = ob[6]; o1.w = ob[7];
    *(ushort4*)(out + (long)node * 256 + lane * 8) = o0;
    *(ushort4*)(out + (long)node * 256 + lane * 8 + 4) = o1;
}

// ---------- GEMM v6.1: B-resident LDS, barrier-free loop + depth-1 A-register pipeline ----------
// R10 counters (MfmaUtil 4.6, VALU 7.4, Occ 22, VGPR 64) => still latency-bound on the
// per-k-step A-loads; compiler did NOT hoist loads across k-steps (minimal VGPR alloc).
// No barriers in this loop, so explicit register prefetch shortens the critical path
// (unlike the barrier-drain-dominated m131-m140 nulls). am[2][4] ring: prefetch step
// kk+1's 4 A-loads BEFORE step kk's MFMA cluster. All indices static after full unroll.
template <int STATS>
__global__ __launch_bounds__(512, 4) void gemm_big(const u16* __restrict__ A, const u16* __restrict__ BT,
                                                   const float* __restrict__ bias, u16* __restrict__ C,
                                                   float* __restrict__ sums, int M) {
    __shared__ u16 ldsB[32768];   // 64 KB: 128 BT-rows x 256 u16, 16B-chunk swizzled
    int tid = threadIdx.x;
    int wave = tid >> 6, lane = tid & 63, l15 = lane & 15, quad = lane >> 4;
    int row0 = blockIdx.x * 256;
    int col0 = blockIdx.y * 128;
    int wr = (wave >> 1) * 64, wc = (wave & 1) * 64;

    // stage B once: 4096 chunks of 16B; chunk slot cl of row n holds source chunk cl^(n&7)
#pragma unroll
    for (int i = 0; i < 8; i++) {
        int g = wave * 8 + i;                 // 64-chunk group 0..63
        int c = g * 64 + lane;                // chunk 0..4095
        int n = c >> 5, cl = c & 31;
        int cs = cl ^ (n & 7);
        gld_lds16(BT + (long)(col0 + n) * 256 + cs * 8, ldsB + g * 512);
    }

    floatx4 acc[4][4];
    floatx4 zero = {0.f, 0.f, 0.f, 0.f};
#pragma unroll
    for (int mi = 0; mi < 4; mi++)
#pragma unroll
        for (int ni = 0; ni < 4; ni++) acc[mi][ni] = zero;

    // hoist per-wave A row bases (tail rows clamped; stores are guarded)
    const u16* arow[4];
#pragma unroll
    for (int i = 0; i < 4; i++)
        arow[i] = A + (long)min(row0 + wr + i * 16 + l15, M - 1) * 256 + quad * 8;

    // preload k-step 0 A-fragments (overlaps B staging flight)
    short8 am[2][4];
#pragma unroll
    for (int i = 0; i < 4; i++) am[0][i] = *(const short8*)(arow[i]);

    __syncthreads();   // B resident (includes vmcnt drain)

    // barrier-free main loop, depth-1 A pipeline:
    // prefetch am[(kk+1)&1] -> ds_read bn -> 16 MFMA on am[kk&1]
#pragma unroll
    for (int kk = 0; kk < 8; kk++) {
        if (kk < 7) {
#pragma unroll
            for (int i = 0; i < 4; i++)
                am[(kk + 1) & 1][i] = *(const short8*)(arow[i] + (kk + 1) * 32);
        }
        short8 bn[4];
#pragma unroll
        for (int i = 0; i < 4; i++) {
            int nb = wc + i * 16 + l15;
            bn[i] = *(const short8*)(ldsB + nb * 256 + (((kk * 4 + quad) ^ (nb & 7)) * 8));
        }
#pragma unroll
        for (int mi = 0; mi < 4; mi++)
#pragma unroll
            for (int ni = 0; ni < 4; ni++)
                acc[mi][ni] = __builtin_amdgcn_mfma_f32_16x16x32_bf16(am[kk & 1][mi], bn[ni], acc[mi][ni], 0, 0, 0);
    }

    // ---- epilogue: bias (+ BN column stats), then coalesced store via Cs transpose ----
    u16* Cs = ldsB;   // 64x136 u16 = 8704, aliases B (dead; barriers below guard reuse)
    float s[4], s2[4];
    if (STATS) {
#pragma unroll
        for (int ni = 0; ni < 4; ni++) { s[ni] = 0.f; s2[ni] = 0.f; }
    }
#pragma unroll
    for (int ni = 0; ni < 4; ni++) {
        int gcol = col0 + wc + ni * 16 + l15;
        float bv = bias[gcol];
#pragma unroll
        for (int mi = 0; mi < 4; mi++)
#pragma unroll
            for (int r = 0; r < 4; r++) {
                float v = acc[mi][ni][r] + bv;
                acc[mi][ni][r] = v;
                if (STATS) {
                    int grow = row0 + wr + mi * 16 + quad * 4 + r;
                    if (grow < M) { s[ni] += v; s2[ni] = fmaf(v, v, s2[ni]); }
                }
            }
    }
    if (STATS) {
#pragma unroll
        for (int ni = 0; ni < 4; ni++) {
            float a = s[ni], b = s2[ni];
            a += __shfl_xor(a, 16, 64); a += __shfl_xor(a, 32, 64);
            b += __shfl_xor(b, 16, 64); b += __shfl_xor(b, 32, 64);
            if (quad == 0) {
                int gcol = col0 + wc + ni * 16 + l15;
                unsafeAtomicAdd(&sums[gcol], a);
                unsafeAtomicAdd(&sums[256 + gcol], b);
            }
        }
    }
    // four 64-row groups: waves with (wave>>1)==h write their 64x64 into Cs; all copy out
#pragma unroll
    for (int h = 0; h < 4; h++) {
        __syncthreads();
        if ((wave >> 1) == h) {
#pragma unroll
            for (int mi = 0; mi < 4; mi++)
#pragma unroll
                for (int ni = 0; ni < 4; ni++)
#pragma unroll
                    for (int r = 0; r < 4; r++)
                        Cs[(mi * 16 + quad * 4 + r) * 136 + wc + ni * 16 + l15] = f2b(acc[mi][ni][r]);
        }
        __syncthreads();
        {   // thread t: row t>>3, 32B chunk t&7 (64 rows x 128 cols)
            int r = tid >> 3, ch = tid & 7;
            int grow = row0 + h * 64 + r;
            if (grow < M) {
                const u16* src = Cs + r * 136 + ch * 16;
                u16* dst = C + (long)grow * 256 + col0 + ch * 16;
                uint4 v0 = *(const uint4*)(src);
                uint4 v1 = *(const uint4*)(src + 8);
                *(uint4*)(dst) = v0;
                *(uint4*)(dst + 8) = v1;
            }
        }
    }
}

// ---------- BN coefficients: scale/shift per column ----------
__global__ __launch_bounds__(256) void bn_coef(const float* __restrict__ sums, const float* __restrict__ gamma,
                                               const float* __restrict__ beta, float* __restrict__ coef, int N) {
    int c = threadIdx.x;
    float invN = 1.0f / (float)N;
    float mean = sums[c] * invN;
    float var = sums[256 + c] * invN - mean * mean;
    float s = gamma[c] * rsqrtf(var + 1e-5f);
    coef[c] = s;
    coef[256 + c] = beta[c] - mean * s;
}

// ---------- predictor v7: 8 waves x 32 queries = 256 q/block, single launch ----------
__global__ __launch_bounds__(512, 2) void predictor(const u16* __restrict__ h2b, const int* __restrict__ e0,
                                                    const int* __restrict__ e1, const u16* __restrict__ pW1T,
                                                    const float* __restrict__ pb1, const float* __restrict__ pW2,
                                                    const float* __restrict__ pb2, float* __restrict__ out, int Q) {
    __shared__ u16 Bs[2][32 * 256];   // 2 x 16 KB double buffer
    int tid = threadIdx.x;
    int wave = tid >> 6, lane = tid & 63, l15 = lane & 15, quad = lane >> 4;

    // async stage of 32 weight rows (phase p) into buf; XOR swizzle folded into source address
    auto stage = [&](int p, u16* buf) {
#pragma unroll
        for (int i = 0; i < 2; i++) {
            int m = wave * 2 + i;                 // 1 KB chunk, 16 chunks = 16 KB
            int nl = m * 2 + (lane >> 5);         // local n row 0..31
            int cl = lane & 31;                   // swizzled 16B slot
            int cs = cl ^ (nl & 7);               // source chunk
            const u16* g = pW1T + (long)(p * 32 + nl) * 256 + cs * 8;
            gld_lds16(g, buf + m * 512);          // lane writes at +lane*16B
        }
    };

    stage(0, Bs[0]);   // in flight under the z-gathers

    int q0 = blockIdx.x * 256;
    short8 za[2][8];
#pragma unroll
    for (int mt = 0; mt < 2; mt++) {
        int q = min(q0 + wave * 32 + mt * 16 + l15, Q - 1);
        long u = (long)e0[q] * 256, v = (long)e1[q] * 256;
#pragma unroll
        for (int ki = 0; ki < 8; ki++) {
            uint4 a = *(const uint4*)(h2b + u + ki * 32 + quad * 8);
            uint4 b = *(const uint4*)(h2b + v + ki * 32 + quad * 8);
            uint4 z;
            z.x = pkmul(a.x, b.x);
            z.y = pkmul(a.y, b.y);
            z.z = pkmul(a.z, b.z);
            z.w = pkmul(a.w, b.w);
            za[mt][ki] = *(short8*)&z;
        }
    }
    float rs[2][4] = {{0.f, 0.f, 0.f, 0.f}, {0.f, 0.f, 0.f, 0.f}};
    floatx4 zero = {0.f, 0.f, 0.f, 0.f};

#pragma unroll
    for (int p = 0; p < 8; p++) {
        if (p < 7) {
            stage(p + 1, Bs[(p + 1) & 1]);
            asm volatile("s_waitcnt vmcnt(2)" ::: "memory");
        } else {
            asm volatile("s_waitcnt vmcnt(0)" ::: "memory");
        }
        __builtin_amdgcn_s_barrier();             // buf[p&1] globally ready
        const u16* buf = Bs[p & 1];
        float bb[2], w2[2];
#pragma unroll
        for (int nt = 0; nt < 2; nt++) {
            int col = p * 32 + nt * 16 + l15;
            bb[nt] = pb1[col];
            w2[nt] = pW2[col];
        }
        floatx4 acc[2][2];
#pragma unroll
        for (int mt = 0; mt < 2; mt++) { acc[mt][0] = zero; acc[mt][1] = zero; }
        __builtin_amdgcn_s_setprio(1);
#pragma unroll
        for (int ki = 0; ki < 8; ki++) {
#pragma unroll
            for (int nt = 0; nt < 2; nt++) {
                int nl = nt * 16 + l15;
                int cs = (ki * 4 + quad) ^ (nl & 7);
                short8 b = *(const short8*)(buf + nl * 256 + cs * 8);
#pragma unroll
                for (int mt = 0; mt < 2; mt++)
                    acc[mt][nt] = __builtin_amdgcn_mfma_f32_16x16x32_bf16(za[mt][ki], b, acc[mt][nt], 0, 0, 0);
            }
        }
        __builtin_amdgcn_s_setprio(0);
        if (p < 7) __builtin_amdgcn_s_barrier();  // all waves done reading buf[p&1]
        // fold this phase's 32 cols into rs (register-only, overlaps next stage's flight)
#pragma unroll
        for (int nt = 0; nt < 2; nt++)
#pragma unroll
            for (int mt = 0; mt < 2; mt++)
#pragma unroll
                for (int r = 0; r < 4; r++)
                    rs[mt][r] = fmaf(fmaxf(acc[mt][nt][r] + bb[nt], 0.f), w2[nt], rs[mt][r]);
    }
    // reduce across the 16 col-lanes
#pragma unroll
    for (int m = 1; m < 16; m <<= 1)
#pragma unroll
        for (int mt = 0; mt < 2; mt++)
#pragma unroll
            for (int r = 0; r < 4; r++)
                rs[mt][r] += __shfl_xor(rs[mt][r], m, 64);
    if (l15 == 0) {
        float b2v = pb2[0];
#pragma unroll
        for (int mt = 0; mt < 2; mt++)
#pragma unroll
            for (int r = 0; r < 4; r++) {
                int qq = q0 + wave * 32 + mt * 16 + quad * 4 + r;
                if (qq < Q) out[qq] = 1.0f / (1.0f + __expf(-(rs[mt][r] + b2v)));
            }
    }
}

extern "C" void kernel_launch(void* const* d_in, const int* in_sizes, int n_in,
                              void* d_out, int out_size, void* d_ws, size_t ws_size,
                              hipStream_t stream) {
    const float* x      = (const float*)d_in[0];
    const int*   adj_row= (const int*)d_in[1];
    const int*   adj_col= (const int*)d_in[2];
    const int*   edges  = (const int*)d_in[3];
    const float* emb    = (const float*)d_in[4];
    const float* W1     = (const float*)d_in[5];
    const float* b1     = (const float*)d_in[6];
    const float* W2     = (const float*)d_in[7];
    const float* b2     = (const float*)d_in[8];
    const float* gamma  = (const float*)d_in[9];
    const float* beta   = (const float*)d_in[10];
    const float* pW1    = (const float*)d_in[11];
    const float* pb1    = (const float*)d_in[12];
    const float* pW2    = (const float*)d_in[13];
    const float* pb2    = (const float*)d_in[14];
    float* out = (float*)d_out;

    int N = in_sizes[0] / 128;
    int E = in_sizes[1];
    int Q = in_sizes[3] / 2;

    char* ws = (char*)d_ws;
    size_t off = 0;
    auto alloc = [&](size_t bytes) -> char* {
        char* p = ws + off;
        off += (bytes + 255) & ~(size_t)255;
        return p;
    };
    // --- contiguous zero-init region: deg_cnt | cursor | sums | gcur (ONE memset) ---
    size_t npad = ((size_t)N * 4 + 255) & ~(size_t)255;
    int*   deg_cnt = (int*)alloc((size_t)N * 4);
    int*   cursor  = (int*)alloc((size_t)N * 4);
    float* sums    = (float*)alloc(512 * 4);
    int*   gcur    = (int*)alloc(4);
    size_t zspan   = npad * 2 + 2048 + 256;
    // --- rest ---
    int*   offs    = (int*)alloc((size_t)N * 4);
    float* dinv    = (float*)alloc((size_t)N * 4);
    int*   scol    = (int*)alloc((size_t)E * 4);
    float* coef    = (float*)alloc(512 * 4);
    u16*   WT      = (u16*)alloc((size_t)3 * 65536 * 2);
    u16*   bufA    = (u16*)alloc((size_t)N * 256 * 2);
    u16*   bufB    = (u16*)alloc((size_t)N * 256 * 2);
    u16*   bufC    = (u16*)alloc((size_t)N * 256 * 2);

    hipMemsetAsync(deg_cnt, 0, zspan, stream);

    int eb  = (E + 255) / 256;
    int NB  = (N + 255) / 256;
    int nb4 = (N * 64 + 255) / 256;
    int ab  = (N + 7) / 8;
    dim3 gemmGrid((N + 255) / 256, 2);

    count_deg<<<eb, 256, 0, stream>>>(adj_row, deg_cnt, E);
    alloc_offs<<<NB, 256, 0, stream>>>(deg_cnt, offs, dinv, gcur, N);
    sort_edges<<<eb, 256, 0, stream>>>(adj_row, adj_col, offs, cursor, scol, E);
    prep_wh<<<768 + nb4, 256, 0, stream>>>(W1, W2, pW1, WT, emb, x, bufA, N);

    // conv1 (commuted): h1 = agg(h0) @ W1 + b1, with fused BN column stats
    aggregate2<0><<<ab, 256, 0, stream>>>(bufA, offs, deg_cnt, scol, dinv, nullptr, bufB, N);
    gemm_big<1><<<gemmGrid, 512, 0, stream>>>(bufB, WT, b1, bufC, sums, N);
    bn_coef<<<1, 256, 0, stream>>>(sums, gamma, beta, coef, N);
    // conv2 (commuted): h2 = agg(relu(bn(h1))) @ W2 + b2, BN+ReLU fused into gather
    aggregate2<1><<<ab, 256, 0, stream>>>(bufC, offs, deg_cnt, scol, dinv, coef, bufB, N);
    gemm_big<0><<<gemmGrid, 512, 0, stream>>>(bufB, WT + 65536, b2, bufC, nullptr, N);
    // link predictor (single launch; round-8 split measured +4.8us wall-clock)
    predictor<<<(Q + 255) / 256, 512, 0, stream>>>(bufC, edges, edges + Q,
                                                   WT + 131072, pb1, pW2, pb2, out, Q);
}